// Round 1
// baseline (318.752 us; speedup 1.0000x reference)
//
#include <hip/hip_runtime.h>
#include <hip/hip_bf16.h>
#include <math.h>

#define CDIM 512
#define TEMP_INV 10.0f
#define MT 64        // rows per block
#define NT 64        // col tile
#define BK 64        // k step
#define NCHUNK 4     // column chunks (grid dim 2)

typedef unsigned short u16;
typedef u16  u16x4 __attribute__((ext_vector_type(4)));
typedef u16  u16x8 __attribute__((ext_vector_type(8)));
typedef __bf16 bf16x8 __attribute__((ext_vector_type(8)));
typedef float  f32x4 __attribute__((ext_vector_type(4)));

static __device__ __forceinline__ float bf2f(u16 u) {
    return __uint_as_float(((unsigned)u) << 16);
}
static __device__ __forceinline__ u16 f2bf(float f) {
    unsigned u = __float_as_uint(f);
    unsigned r = (u + 0x7FFFu + ((u >> 16) & 1u)) >> 16;  // RNE
    return (u16)r;
}

// ---------------------------------------------------------------------------
// Kernel 1: row-normalize (fp32) and split into bf16 hi/lo pairs.
// One wave per row; 4 waves per block; rows [0,n) = x, [n,2n) = quantized.
// ---------------------------------------------------------------------------
__global__ __launch_bounds__(256) void norm_split_kernel(
    const float* __restrict__ x, const float* __restrict__ q,
    u16* __restrict__ xh, u16* __restrict__ xl,
    u16* __restrict__ qh, u16* __restrict__ ql, int n)
{
    int wave = blockIdx.x * 4 + (threadIdx.x >> 6);
    int lane = threadIdx.x & 63;
    const float* src; u16* dh; u16* dl; int row;
    if (wave < n) { src = x; dh = xh; dl = xl; row = wave; }
    else          { src = q; dh = qh; dl = ql; row = wave - n; }

    const float4* p = reinterpret_cast<const float4*>(src + (size_t)row * CDIM);
    float4 a = p[lane * 2];
    float4 b = p[lane * 2 + 1];
    float v[8] = {a.x, a.y, a.z, a.w, b.x, b.y, b.z, b.w};
    float ss = 0.f;
#pragma unroll
    for (int j = 0; j < 8; ++j) ss += v[j] * v[j];
#pragma unroll
    for (int off = 32; off; off >>= 1) ss += __shfl_xor(ss, off);
    float scale = 1.0f / fmaxf(sqrtf(ss), 1e-12f);

    u16 h[8] __attribute__((aligned(16)));
    u16 l[8] __attribute__((aligned(16)));
#pragma unroll
    for (int j = 0; j < 8; ++j) {
        float f = v[j] * scale;
        u16 hb = f2bf(f);
        float lr = f - bf2f(hb);   // exact in fp32
        h[j] = hb;
        l[j] = f2bf(lr);
    }
    size_t base = (size_t)row * CDIM + lane * 8;
    *(u16x8*)&dh[base] = *(u16x8*)h;
    *(u16x8*)&dl[base] = *(u16x8*)l;
}

// ---------------------------------------------------------------------------
// Kernel 2: fused sim GEMM + online logsumexp/argmax per row.
// Block = 256 threads (4 waves, 2x2), owns MT=64 rows x one 2048-col chunk.
// 3-pass split-precision MFMA: hi*hi + hi*lo + lo*hi (fp32 accumulate).
// ---------------------------------------------------------------------------
__global__ __launch_bounds__(256) void sim_main_kernel(
    const u16* __restrict__ xh, const u16* __restrict__ xl,
    const u16* __restrict__ qh, const u16* __restrict__ ql,
    float* __restrict__ pm, float* __restrict__ pl,
    float* __restrict__ pbv, int* __restrict__ pbi, int n)
{
    const int nrb = n / MT;                 // 128 row-blocks
    const int rb  = blockIdx.x % nrb;
    const int ch  = blockIdx.x / nrb;
    const int chunk_cols = n / NCHUNK;      // 2048
    const int row0 = rb * MT;
    const int col0 = ch * chunk_cols;

    __shared__ u16 Ah[64][72], Al[64][72], Bh[64][72], Bl[64][72]; // +8 pad: kills 16-way bank conflict
    __shared__ float simt[64][68];                                  // 272B stride: 16B-aligned rows
    __shared__ float rm[64], rl[64], rbv[64];
    __shared__ int   rbi[64];

    const int t    = threadIdx.x;
    const int lane = t & 63;
    const int wid  = t >> 6;
    const int wm   = wid >> 1;   // wave row 0..1
    const int wn   = wid & 1;    // wave col 0..1

    if (t < 64) { rm[t] = -1e30f; rl[t] = 0.f; rbv[t] = -1e30f; rbi[t] = 0; }

    for (int ct = 0; ct < chunk_cols / NT; ++ct) {
        const int c0 = col0 + ct * NT;
        f32x4 acc[2][2];
        const f32x4 zero = {0.f, 0.f, 0.f, 0.f};
#pragma unroll
        for (int i = 0; i < 2; ++i)
#pragma unroll
            for (int j = 0; j < 2; ++j) acc[i][j] = zero;

        for (int ks = 0; ks < CDIM; ks += BK) {
            __syncthreads();   // LDS reuse guard (prev reads done)
#pragma unroll
            for (int it = 0; it < 2; ++it) {
                int id = it * 256 + t;
                int r  = id >> 3;
                int k8 = (id & 7) * 8;
                size_t ga = (size_t)(row0 + r) * CDIM + ks + k8;
                size_t gb = (size_t)(c0  + r) * CDIM + ks + k8;
                *(u16x8*)&Ah[r][k8] = *(const u16x8*)&xh[ga];
                *(u16x8*)&Al[r][k8] = *(const u16x8*)&xl[ga];
                *(u16x8*)&Bh[r][k8] = *(const u16x8*)&qh[gb];
                *(u16x8*)&Bl[r][k8] = *(const u16x8*)&ql[gb];
            }
            __syncthreads();
#pragma unroll
            for (int ku = 0; ku < 2; ++ku) {
                const int kk = ku * 32 + (lane >> 4) * 8;
#pragma unroll
                for (int mf = 0; mf < 2; ++mf) {
                    const int ar = wm * 32 + mf * 16 + (lane & 15);
                    bf16x8 avh = *(const bf16x8*)&Ah[ar][kk];
                    bf16x8 avl = *(const bf16x8*)&Al[ar][kk];
#pragma unroll
                    for (int nf = 0; nf < 2; ++nf) {
                        const int br = wn * 32 + nf * 16 + (lane & 15);
                        bf16x8 bvh = *(const bf16x8*)&Bh[br][kk];
                        bf16x8 bvl = *(const bf16x8*)&Bl[br][kk];
                        acc[mf][nf] = __builtin_amdgcn_mfma_f32_16x16x32_bf16(avh, bvh, acc[mf][nf], 0, 0, 0);
                        acc[mf][nf] = __builtin_amdgcn_mfma_f32_16x16x32_bf16(avh, bvl, acc[mf][nf], 0, 0, 0);
                        acc[mf][nf] = __builtin_amdgcn_mfma_f32_16x16x32_bf16(avl, bvh, acc[mf][nf], 0, 0, 0);
                    }
                }
            }
        }

        // ------- epilogue: 64x64 sim tile -> online row stats -------
        __syncthreads();
#pragma unroll
        for (int mf = 0; mf < 2; ++mf)
#pragma unroll
            for (int nf = 0; nf < 2; ++nf) {
                int rr = wm * 32 + mf * 16 + (lane >> 4) * 4;  // C/D: row=(lane>>4)*4+reg
                int cc = wn * 32 + nf * 16 + (lane & 15);      //      col=lane&15
#pragma unroll
                for (int r = 0; r < 4; ++r)
                    simt[rr + r][cc] = acc[mf][nf][r] * TEMP_INV;
            }
        __syncthreads();
        {
            const int row = t >> 2, slot = t & 3;   // 4 threads per row
            float vals[16];
#pragma unroll
            for (int c4 = 0; c4 < 4; ++c4) {
                float4 vv = *(const float4*)&simt[row][slot * 16 + c4 * 4];
                vals[c4 * 4 + 0] = vv.x; vals[c4 * 4 + 1] = vv.y;
                vals[c4 * 4 + 2] = vv.z; vals[c4 * 4 + 3] = vv.w;
            }
            float lm = -1e30f; int li = 0;
#pragma unroll
            for (int c = 0; c < 16; ++c) {
                if (vals[c] > lm) { lm = vals[c]; li = c0 + slot * 16 + c; }
            }
#pragma unroll
            for (int off = 1; off < 4; off <<= 1) {   // max/argmax over 4 slots, first-index tiebreak
                float ov = __shfl_xor(lm, off);
                int   oi = __shfl_xor(li, off);
                if (ov > lm || (ov == lm && oi < li)) { lm = ov; li = oi; }
            }
            float newm = fmaxf(rm[row], lm);
            float pe = 0.f;
#pragma unroll
            for (int c = 0; c < 16; ++c) pe += __expf(vals[c] - newm);
#pragma unroll
            for (int off = 1; off < 4; off <<= 1) pe += __shfl_xor(pe, off);
            if (slot == 0) {
                rl[row] = rl[row] * __expf(rm[row] - newm) + pe;
                rm[row] = newm;
                if (lm > rbv[row]) { rbv[row] = lm; rbi[row] = li; }  // strict >: first occurrence wins
            }
        }
    }
    __syncthreads();
    if (t < 64) {
        int gr = row0 + t;
        size_t o = (size_t)ch * n + gr;
        pm[o] = rm[t]; pl[o] = rl[t]; pbv[o] = rbv[t]; pbi[o] = rbi[t];
    }
}

// ---------------------------------------------------------------------------
// Kernel 3: per-row merge of chunk partials + fp32 diag + loss_i/correct_i.
// One wave per row.
// ---------------------------------------------------------------------------
__global__ __launch_bounds__(256) void merge_kernel(
    const u16* __restrict__ xh, const u16* __restrict__ xl,
    const u16* __restrict__ qh, const u16* __restrict__ ql,
    const float* __restrict__ pm, const float* __restrict__ pl,
    const float* __restrict__ pbv, const int* __restrict__ pbi,
    float* __restrict__ loss_arr, float* __restrict__ corr_arr, int n)
{
    int i    = blockIdx.x * 4 + (threadIdx.x >> 6);
    int lane = threadIdx.x & 63;
    if (i >= n) return;

    size_t base = (size_t)i * CDIM + lane * 8;
    float d = 0.f;
#pragma unroll
    for (int jj = 0; jj < 2; ++jj) {
        u16x4 hx = *(const u16x4*)&xh[base + jj * 4];
        u16x4 lx = *(const u16x4*)&xl[base + jj * 4];
        u16x4 hq = *(const u16x4*)&qh[base + jj * 4];
        u16x4 lq = *(const u16x4*)&ql[base + jj * 4];
#pragma unroll
        for (int e = 0; e < 4; ++e) {
            float xf = bf2f(hx[e]) + bf2f(lx[e]);
            float qf = bf2f(hq[e]) + bf2f(lq[e]);
            d += xf * qf;
        }
    }
#pragma unroll
    for (int off = 32; off; off >>= 1) d += __shfl_xor(d, off);

    if (lane == 0) {
        float M = -1e30f;
        for (int c = 0; c < NCHUNK; ++c) M = fmaxf(M, pm[(size_t)c * n + i]);
        float L = 0.f;
        for (int c = 0; c < NCHUNK; ++c) L += pl[(size_t)c * n + i] * __expf(pm[(size_t)c * n + i] - M);
        float logZ = M + logf(L);
        float bv = -1e30f; int bi = 0;
        for (int c = 0; c < NCHUNK; ++c) {   // ascending: lower chunk wins ties
            float v  = pbv[(size_t)c * n + i];
            int   ii = pbi[(size_t)c * n + i];
            if (v > bv || (v == bv && ii < bi)) { bv = v; bi = ii; }
        }
        loss_arr[i] = logZ - d * TEMP_INV;
        corr_arr[i] = (bi == i) ? 1.0f : 0.0f;
    }
}

// ---------------------------------------------------------------------------
// Kernel 4: deterministic single-block mean reduction -> d_out[0..1]
// ---------------------------------------------------------------------------
__global__ __launch_bounds__(256) void finalize_kernel(
    const float* __restrict__ loss_arr, const float* __restrict__ corr_arr,
    float* __restrict__ out, int n)
{
    float a = 0.f, b = 0.f;
    for (int i = threadIdx.x; i < n; i += 256) { a += loss_arr[i]; b += corr_arr[i]; }
#pragma unroll
    for (int off = 32; off; off >>= 1) { a += __shfl_xor(a, off); b += __shfl_xor(b, off); }
    __shared__ float sa[4], sb[4];
    int wid = threadIdx.x >> 6, lane = threadIdx.x & 63;
    if (lane == 0) { sa[wid] = a; sb[wid] = b; }
    __syncthreads();
    if (threadIdx.x == 0) {
        out[0] = (sa[0] + sa[1] + sa[2] + sa[3]) / n;
        out[1] = (sb[0] + sb[1] + sb[2] + sb[3]) / n;
    }
}

extern "C" void kernel_launch(void* const* d_in, const int* in_sizes, int n_in,
                              void* d_out, int out_size, void* d_ws, size_t ws_size,
                              hipStream_t stream)
{
    const float* x = (const float*)d_in[0];
    const float* q = (const float*)d_in[1];
    const int n = in_sizes[0] / CDIM;   // 8192

    char* ws = (char*)d_ws;
    size_t sz_bf = (size_t)n * CDIM * sizeof(u16);   // 8 MB each
    u16* xh = (u16*)(ws);
    u16* xl = (u16*)(ws + sz_bf);
    u16* qh = (u16*)(ws + 2 * sz_bf);
    u16* ql = (u16*)(ws + 3 * sz_bf);
    char* p = ws + 4 * sz_bf;
    float* pm  = (float*)p; p += (size_t)NCHUNK * n * 4;
    float* pl  = (float*)p; p += (size_t)NCHUNK * n * 4;
    float* pbv = (float*)p; p += (size_t)NCHUNK * n * 4;
    int*   pbi = (int*)p;   p += (size_t)NCHUNK * n * 4;
    float* loss_arr = (float*)p; p += (size_t)n * 4;
    float* corr_arr = (float*)p;

    norm_split_kernel<<<(2 * n) / 4, 256, 0, stream>>>(x, q, xh, xl, qh, ql, n);

    const int nrb = n / MT;   // 128
    sim_main_kernel<<<nrb * NCHUNK, 256, 0, stream>>>(xh, xl, qh, ql, pm, pl, pbv, pbi, n);

    merge_kernel<<<n / 4, 256, 0, stream>>>(xh, xl, qh, ql, pm, pl, pbv, pbi,
                                            loss_arr, corr_arr, n);

    finalize_kernel<<<1, 256, 0, stream>>>(loss_arr, corr_arr, (float*)d_out, n);
}

// Round 2
// 284.872 us; speedup vs baseline: 1.1189x; 1.1189x over previous
//
#include <hip/hip_runtime.h>
#include <hip/hip_bf16.h>
#include <math.h>

#define CDIM 512
#define NROW 8192
#define TEMP_INV 10.0f
#define NTILE 24            // K tiles: 1536/64 (3 split-precision passes concatenated)
#define NHALF (NTILE * 4)   // half-tiles: A0,A1,B0,B1 per K-tile
#define NCB 32              // column blocks of 256

typedef unsigned short u16;
typedef u16  u16x4 __attribute__((ext_vector_type(4)));
typedef u16  u16x8 __attribute__((ext_vector_type(8)));
typedef __bf16 bf16x8 __attribute__((ext_vector_type(8)));
typedef float  f32x4 __attribute__((ext_vector_type(4)));

static __device__ __forceinline__ float bf2f(u16 u) {
    return __uint_as_float(((unsigned)u) << 16);
}
static __device__ __forceinline__ u16 f2bf(float f) {
    unsigned u = __float_as_uint(f);
    return (u16)((u + 0x7FFFu + ((u >> 16) & 1u)) >> 16);  // RNE
}

static __device__ __forceinline__ void gload_lds16(const u16* g, char* l) {
    __builtin_amdgcn_global_load_lds(
        (const __attribute__((address_space(1))) void*)g,
        (__attribute__((address_space(3))) void*)l, 16, 0, 0);
}

// ---------------------------------------------------------------------------
// Kernel 1: row-normalize (fp32) and split into bf16 hi/lo pairs. (unchanged)
// ---------------------------------------------------------------------------
__global__ __launch_bounds__(256) void norm_split_kernel(
    const float* __restrict__ x, const float* __restrict__ q,
    u16* __restrict__ xh, u16* __restrict__ xl,
    u16* __restrict__ qh, u16* __restrict__ ql, int n)
{
    int wave = blockIdx.x * 4 + (threadIdx.x >> 6);
    int lane = threadIdx.x & 63;
    const float* src; u16* dh; u16* dl; int row;
    if (wave < n) { src = x; dh = xh; dl = xl; row = wave; }
    else          { src = q; dh = qh; dl = ql; row = wave - n; }

    const float4* p = reinterpret_cast<const float4*>(src + (size_t)row * CDIM);
    float4 a = p[lane * 2];
    float4 b = p[lane * 2 + 1];
    float v[8] = {a.x, a.y, a.z, a.w, b.x, b.y, b.z, b.w};
    float ss = 0.f;
#pragma unroll
    for (int j = 0; j < 8; ++j) ss += v[j] * v[j];
#pragma unroll
    for (int off = 32; off; off >>= 1) ss += __shfl_xor(ss, off);
    float scale = 1.0f / fmaxf(sqrtf(ss), 1e-12f);

    u16 h[8] __attribute__((aligned(16)));
    u16 l[8] __attribute__((aligned(16)));
#pragma unroll
    for (int j = 0; j < 8; ++j) {
        float f = v[j] * scale;
        u16 hb = f2bf(f);
        float lr = f - bf2f(hb);
        h[j] = hb;
        l[j] = f2bf(lr);
    }
    size_t base = (size_t)row * CDIM + lane * 8;
    *(u16x8*)&dh[base] = *(u16x8*)h;
    *(u16x8*)&dl[base] = *(u16x8*)l;
}

// ---------------------------------------------------------------------------
// Kernel 2: 256x256-tile 8-phase pipelined GEMM (K=1536 via segment pointers)
// with fused per-row online logsumexp/argmax epilogue.
// 512 threads = 8 waves (2 wm x 4 wn), each wave owns 128x64 of C.
// LDS: 2 dbuf x (A 256x64 + B 256x64) bf16 = 128 KB, XOR-swizzled.
// ---------------------------------------------------------------------------
__global__ __launch_bounds__(512, 2) void sim_main_kernel(
    const u16* __restrict__ xh, const u16* __restrict__ xl,
    const u16* __restrict__ qh, const u16* __restrict__ ql,
    float* __restrict__ pm, float* __restrict__ pl, int* __restrict__ pbi)
{
    extern __shared__ __align__(16) char smem[];
    const int t = threadIdx.x, lane = t & 63, wid = t >> 6;
    const int wm = wid >> 2, wn = wid & 3;

    // XCD-aware bijective swizzle (1024 % 8 == 0)
    const int orig = blockIdx.x;
    const int wg = (orig & 7) * 128 + (orig >> 3);
    const int rb = wg & 31, cb = wg >> 5;
    const int row0 = rb * 256, col0 = cb * 256;

    // hoisted swizzled read offsets: byte ^= ((row&7)<<4); row&7 == lane&7
    const unsigned xr  = ((unsigned)(lane & 7)) << 4;
    const unsigned kx0 = (((unsigned)(lane >> 4)) * 16u) ^ xr;
    const unsigned kx1 = (64u + ((unsigned)(lane >> 4)) * 16u) ^ xr;
    const unsigned aoff = (unsigned)wm * 16384u + (unsigned)(lane & 15) * 128u;
    const unsigned boff = 32768u + (unsigned)(wn >> 1) * 16384u
                        + (unsigned)((wn & 1) * 64 + (lane & 15)) * 128u;

    f32x4 acc[8][4];
#pragma unroll
    for (int i = 0; i < 8; ++i)
#pragma unroll
        for (int j = 0; j < 4; ++j) acc[i][j] = (f32x4){0.f, 0.f, 0.f, 0.f};

    // stage one half-tile h: 8 waves x 2 x global_load_lds(16B) = 16 KB
    // LDS dest linear; SOURCE pre-swizzled with the same involution.
    auto stage = [&](int h) {
        const int kt = h >> 2, wch = h & 3;
        const unsigned region = ((unsigned)(kt & 1)) * 65536u + (unsigned)wch * 16384u;
        const int half = wch & 1;
        const int seg = kt >> 3;                       // 0: hh, 1: lh, 2: hl
        const u16* mat; int rbase;
        if (wch < 2) { mat = (seg == 1) ? xl : xh; rbase = row0 + half * 128; }
        else         { mat = (seg == 2) ? ql : qh; rbase = col0 + half * 128; }
        const int kc0 = (kt & 7) * 64;
#pragma unroll
        for (int j = 0; j < 2; ++j) {
            unsigned cbo = (unsigned)(wid * 2 + j) * 1024u;
            unsigned so  = cbo + (((unsigned)lane * 16u) ^ ((((unsigned)lane >> 3) & 7u) << 4));
            int rih = (int)(so >> 7);
            int ke  = (int)((so & 127u) >> 1);
            const u16* g = mat + (size_t)(rbase + rih) * CDIM + kc0 + ke;
            gload_lds16(g, smem + region + cbo);
        }
    };

    // ---- prologue: stage halves 0..6 (lead 7), paced drains ----
    stage(0); stage(1); stage(2); stage(3);
    asm volatile("s_waitcnt vmcnt(4)" ::: "memory");
    stage(4); stage(5); stage(6);
    asm volatile("s_waitcnt vmcnt(6)" ::: "memory");
    asm volatile("" ::: "memory");
    __builtin_amdgcn_s_barrier();
    asm volatile("" ::: "memory");

    // ---- main loop: 4 phases per K-tile ----
    for (int kt = 0; kt < NTILE; ++kt) {
        const unsigned bufb = ((unsigned)(kt & 1)) * 65536u;
        bf16x8 bfr[4][2];
        bf16x8 afr[2][2];
#pragma unroll
        for (int q = 0; q < 4; ++q) {
            // ds-load register subtiles for this phase
            if (q == 0) {
#pragma unroll
                for (int nf = 0; nf < 4; ++nf) {
                    bfr[nf][0] = *(const bf16x8*)(smem + bufb + boff + nf * 2048u + kx0);
                    bfr[nf][1] = *(const bf16x8*)(smem + bufb + boff + nf * 2048u + kx1);
                }
            }
#pragma unroll
            for (int m = 0; m < 2; ++m) {
                const unsigned mo = (unsigned)(q * 2 + m) * 2048u;
                afr[m][0] = *(const bf16x8*)(smem + bufb + aoff + mo + kx0);
                afr[m][1] = *(const bf16x8*)(smem + bufb + aoff + mo + kx1);
            }
            // prefetch one half-tile (lead 7)
            {
                int h = kt * 4 + q + 7;
                if (h < NHALF) stage(h);
            }
            asm volatile("" ::: "memory");
            __builtin_amdgcn_s_barrier();
            asm volatile("s_waitcnt lgkmcnt(0)" ::: "memory");
            __builtin_amdgcn_s_setprio(1);
#pragma unroll
            for (int ks = 0; ks < 2; ++ks)
#pragma unroll
                for (int m = 0; m < 2; ++m)
#pragma unroll
                    for (int nf = 0; nf < 4; ++nf)
                        acc[q * 2 + m][nf] = __builtin_amdgcn_mfma_f32_16x16x32_bf16(
                            afr[m][ks], bfr[nf][ks], acc[q * 2 + m][nf], 0, 0, 0);
            __builtin_amdgcn_s_setprio(0);
            if (q == 3) {
                if (kt < NTILE - 2)      { asm volatile("s_waitcnt vmcnt(6)" ::: "memory"); }
                else if (kt == NTILE - 2){ asm volatile("s_waitcnt vmcnt(0)" ::: "memory"); }
            }
            asm volatile("" ::: "memory");
            __builtin_amdgcn_s_barrier();
            asm volatile("" ::: "memory");
        }
    }

    // ---- epilogue: per-row (max, sum-exp, argmax) from accumulators ----
    // C/D layout: row = (lane>>4)*4 + reg, col = lane&15 (verified R1).
    float* sm = (float*)smem;            // [256][4] per-wn row max (sim units)
    float* sl = (float*)(smem + 4096);   // [256][4] sum exp
    int*   si = (int*)(smem + 8192);     // [256][4] argmax col
    const int g = lane >> 4;
#pragma unroll
    for (int mf = 0; mf < 8; ++mf) {
#pragma unroll
        for (int r = 0; r < 4; ++r) {
            const int ci = col0 + wn * 64 + (lane & 15);
            float vmax = acc[mf][0][r];
            int cbest = ci;
#pragma unroll
            for (int nf = 1; nf < 4; ++nf) {
                float v = acc[mf][nf][r];
                if (v > vmax) { vmax = v; cbest = ci + nf * 16; }
            }
#pragma unroll
            for (int m = 1; m < 16; m <<= 1) {
                float ov = __shfl_xor(vmax, m);
                int   oi = __shfl_xor(cbest, m);
                if (ov > vmax || (ov == vmax && oi < cbest)) { vmax = ov; cbest = oi; }
            }
            float s = 0.f;
#pragma unroll
            for (int nf = 0; nf < 4; ++nf)
                s += __expf((acc[mf][nf][r] - vmax) * TEMP_INV);
#pragma unroll
            for (int m = 1; m < 16; m <<= 1) s += __shfl_xor(s, m);
            if ((lane & 15) == 0) {
                int rl_ = wm * 128 + mf * 16 + g * 4 + r;
                sm[rl_ * 4 + wn] = vmax * TEMP_INV;   // sim units
                sl[rl_ * 4 + wn] = s;
                si[rl_ * 4 + wn] = cbest;
            }
        }
    }
    __syncthreads();
    if (t < 256) {
        float M = sm[t * 4];
#pragma unroll
        for (int w = 1; w < 4; ++w) M = fmaxf(M, sm[t * 4 + w]);
        float L = 0.f;
#pragma unroll
        for (int w = 0; w < 4; ++w) L += sl[t * 4 + w] * __expf(sm[t * 4 + w] - M);
        float bv = -1e30f; int bi = 0;
#pragma unroll
        for (int w = 0; w < 4; ++w) {      // ascending wn: first-index tiebreak
            float v = sm[t * 4 + w];
            if (v > bv) { bv = v; bi = si[t * 4 + w]; }
        }
        size_t o = (size_t)cb * NROW + row0 + t;
        pm[o] = M; pl[o] = L; pbi[o] = bi;
    }
}

// ---------------------------------------------------------------------------
// Kernel 3: per-row merge of 32 chunk partials + fp32 diag + loss_i/correct_i.
// ---------------------------------------------------------------------------
__global__ __launch_bounds__(256) void merge_kernel(
    const u16* __restrict__ xh, const u16* __restrict__ xl,
    const u16* __restrict__ qh, const u16* __restrict__ ql,
    const float* __restrict__ pm, const float* __restrict__ pl,
    const int* __restrict__ pbi,
    float* __restrict__ loss_arr, float* __restrict__ corr_arr, int n)
{
    int i    = blockIdx.x * 4 + (threadIdx.x >> 6);
    int lane = threadIdx.x & 63;
    if (i >= n) return;

    size_t base = (size_t)i * CDIM + lane * 8;
    float d = 0.f;
#pragma unroll
    for (int jj = 0; jj < 2; ++jj) {
        u16x4 hx = *(const u16x4*)&xh[base + jj * 4];
        u16x4 lx = *(const u16x4*)&xl[base + jj * 4];
        u16x4 hq = *(const u16x4*)&qh[base + jj * 4];
        u16x4 lq = *(const u16x4*)&ql[base + jj * 4];
#pragma unroll
        for (int e = 0; e < 4; ++e) {
            float xf = bf2f(hx[e]) + bf2f(lx[e]);
            float qf = bf2f(hq[e]) + bf2f(lq[e]);
            d += xf * qf;
        }
    }
#pragma unroll
    for (int off = 32; off; off >>= 1) d += __shfl_xor(d, off);

    if (lane == 0) {
        float M = -1e30f;
        for (int c = 0; c < NCB; ++c) M = fmaxf(M, pm[(size_t)c * n + i]);
        float L = 0.f;
        for (int c = 0; c < NCB; ++c) L += pl[(size_t)c * n + i] * __expf(pm[(size_t)c * n + i] - M);
        float logZ = M + logf(L);
        float bv = -1e30f; int bi = 0;
        for (int c = 0; c < NCB; ++c) {   // ascending: lower chunk wins ties
            float v = pm[(size_t)c * n + i];
            if (v > bv) { bv = v; bi = pbi[(size_t)c * n + i]; }
        }
        loss_arr[i] = logZ - d * TEMP_INV;
        corr_arr[i] = (bi == i) ? 1.0f : 0.0f;
    }
}

// ---------------------------------------------------------------------------
// Kernel 4: deterministic single-block mean reduction -> d_out[0..1]
// ---------------------------------------------------------------------------
__global__ __launch_bounds__(256) void finalize_kernel(
    const float* __restrict__ loss_arr, const float* __restrict__ corr_arr,
    float* __restrict__ out, int n)
{
    float a = 0.f, b = 0.f;
    for (int i = threadIdx.x; i < n; i += 256) { a += loss_arr[i]; b += corr_arr[i]; }
#pragma unroll
    for (int off = 32; off; off >>= 1) { a += __shfl_xor(a, off); b += __shfl_xor(b, off); }
    __shared__ float sa[4], sb[4];
    int wid = threadIdx.x >> 6, lane = threadIdx.x & 63;
    if (lane == 0) { sa[wid] = a; sb[wid] = b; }
    __syncthreads();
    if (threadIdx.x == 0) {
        out[0] = (sa[0] + sa[1] + sa[2] + sa[3]) / n;
        out[1] = (sb[0] + sb[1] + sb[2] + sb[3]) / n;
    }
}

extern "C" void kernel_launch(void* const* d_in, const int* in_sizes, int n_in,
                              void* d_out, int out_size, void* d_ws, size_t ws_size,
                              hipStream_t stream)
{
    const float* x = (const float*)d_in[0];
    const float* q = (const float*)d_in[1];
    const int n = in_sizes[0] / CDIM;   // 8192

    char* ws = (char*)d_ws;
    size_t sz_bf = (size_t)n * CDIM * sizeof(u16);   // 8 MB each
    u16* xh = (u16*)(ws);
    u16* xl = (u16*)(ws + sz_bf);
    u16* qh = (u16*)(ws + 2 * sz_bf);
    u16* ql = (u16*)(ws + 3 * sz_bf);
    char* p = ws + 4 * sz_bf;
    float* pm  = (float*)p; p += (size_t)NCB * n * 4;
    float* pl  = (float*)p; p += (size_t)NCB * n * 4;
    int*   pbi = (int*)p;   p += (size_t)NCB * n * 4;
    float* loss_arr = (float*)p; p += (size_t)n * 4;
    float* corr_arr = (float*)p;

    norm_split_kernel<<<(2 * n) / 4, 256, 0, stream>>>(x, q, xh, xl, qh, ql, n);

    sim_main_kernel<<<(n / 256) * (n / 256), 512, 131072, stream>>>(
        xh, xl, qh, ql, pm, pl, pbi);

    merge_kernel<<<n / 4, 256, 0, stream>>>(xh, xl, qh, ql, pm, pl, pbi,
                                            loss_arr, corr_arr, n);

    finalize_kernel<<<1, 256, 0, stream>>>(loss_arr, corr_arr, (float*)d_out, n);
}

// Round 3
// 175.034 us; speedup vs baseline: 1.8211x; 1.6275x over previous
//
#include <hip/hip_runtime.h>
#include <hip/hip_bf16.h>
#include <math.h>

#define CDIM 512
#define NROW 8192
#define TEMP_INV 10.0f
#define NTILE 8             // K tiles: 512/64
#define NHALF (NTILE * 4)   // half-tiles: B0,B1,A0,A1 per K-tile
#define NCB 32              // column blocks of 256

typedef unsigned short u16;
typedef u16  u16x8 __attribute__((ext_vector_type(8)));
typedef __bf16 bf16x8 __attribute__((ext_vector_type(8)));
typedef float  f32x4 __attribute__((ext_vector_type(4)));

static __device__ __forceinline__ float bf2f(u16 u) {
    return __uint_as_float(((unsigned)u) << 16);
}
static __device__ __forceinline__ u16 f2bf(float f) {
    unsigned u = __float_as_uint(f);
    return (u16)((u + 0x7FFFu + ((u >> 16) & 1u)) >> 16);  // RNE
}

static __device__ __forceinline__ void gload_lds16(const u16* g, char* l) {
    __builtin_amdgcn_global_load_lds(
        (const __attribute__((address_space(1))) void*)g,
        (__attribute__((address_space(3))) void*)l, 16, 0, 0);
}

// ---------------------------------------------------------------------------
// Kernel 1: row-normalize (fp32 math) -> bf16 (RNE). One wave per row.
// ---------------------------------------------------------------------------
__global__ __launch_bounds__(256) void norm_split_kernel(
    const float* __restrict__ x, const float* __restrict__ q,
    u16* __restrict__ xh, u16* __restrict__ qh, int n)
{
    int wave = blockIdx.x * 4 + (threadIdx.x >> 6);
    int lane = threadIdx.x & 63;
    const float* src; u16* dh; int row;
    if (wave < n) { src = x; dh = xh; row = wave; }
    else          { src = q; dh = qh; row = wave - n; }

    const float4* p = reinterpret_cast<const float4*>(src + (size_t)row * CDIM);
    float4 a = p[lane * 2];
    float4 b = p[lane * 2 + 1];
    float v[8] = {a.x, a.y, a.z, a.w, b.x, b.y, b.z, b.w};
    float ss = 0.f;
#pragma unroll
    for (int j = 0; j < 8; ++j) ss += v[j] * v[j];
#pragma unroll
    for (int off = 32; off; off >>= 1) ss += __shfl_xor(ss, off);
    float scale = 1.0f / fmaxf(sqrtf(ss), 1e-12f);

    u16 h[8] __attribute__((aligned(16)));
#pragma unroll
    for (int j = 0; j < 8; ++j) h[j] = f2bf(v[j] * scale);
    *(u16x8*)&dh[(size_t)row * CDIM + lane * 8] = *(u16x8*)h;
}

// ---------------------------------------------------------------------------
// Kernel 2: 256x256-tile 8-phase pipelined bf16 GEMM (K=512) with fused
// per-row online logsumexp/argmax epilogue.
// Half-tile map (h&3): 0=B0, 1=B1, 2=A0, 3=A1. Lead-7 staging =>
// read-buffer overwrites during kt: B0@q1, B1@q2, A0@q3 (kt+2 halves) --
// all regions are architecturally drained >=1 barrier before overwrite:
//   B fully read+waited at q0's MFMA; A frags prefetched one phase early,
//   q3-frag reads drained by explicit lgkmcnt(0) before q2's closing barrier.
// ---------------------------------------------------------------------------
__global__ __launch_bounds__(512, 2) void sim_main_kernel(
    const u16* __restrict__ xh, const u16* __restrict__ qh,
    float* __restrict__ pm, float* __restrict__ pl, int* __restrict__ pbi)
{
    extern __shared__ __align__(16) char smem[];
    const int t = threadIdx.x, lane = t & 63, wid = t >> 6;
    const int wm = wid >> 2, wn = wid & 3;

    // XCD-aware bijective swizzle (1024 % 8 == 0)
    const int orig = blockIdx.x;
    const int wg = (orig & 7) * 128 + (orig >> 3);
    const int rb = wg & 31, cb = wg >> 5;
    const int row0 = rb * 256, col0 = cb * 256;

    // swizzled read offsets: byte ^= ((row&7)<<4); row&7 == lane&7
    const unsigned xr  = ((unsigned)(lane & 7)) << 4;
    const unsigned kx0 = (((unsigned)(lane >> 4)) * 16u) ^ xr;
    const unsigned kx1 = (64u + ((unsigned)(lane >> 4)) * 16u) ^ xr;
    const unsigned aoff = 32768u + ((unsigned)wm * 128u + (unsigned)(lane & 15)) * 128u;
    const unsigned boff = ((unsigned)wn * 64u + (unsigned)(lane & 15)) * 128u;

    // staging: LDS dest linear, SOURCE pre-swizzled (same involution).
    // Per-lane source bases hoisted out of the loop (h only shifts by
    // uniform offsets).
    const unsigned cbo0 = (unsigned)(wid * 2) * 1024u, cbo1 = cbo0 + 1024u;
    const u16 *sA0, *sA1, *sB0, *sB1;
    {
        unsigned sl0 = ((unsigned)lane * 16u) ^ ((((unsigned)lane >> 3) & 7u) << 4);
        unsigned so0 = cbo0 + sl0, so1 = cbo1 + sl0;
        int r0 = (int)(so0 >> 7), k0 = (int)((so0 & 127u) >> 1);
        int r1 = (int)(so1 >> 7), k1 = (int)((so1 & 127u) >> 1);
        sA0 = xh + (size_t)(row0 + r0) * CDIM + k0;
        sA1 = xh + (size_t)(row0 + r1) * CDIM + k1;
        sB0 = qh + (size_t)(col0 + r0) * CDIM + k0;
        sB1 = qh + (size_t)(col0 + r1) * CDIM + k1;
    }

    auto stage = [&](int h) {
        const int wch = h & 3;
        const unsigned region = ((unsigned)((h >> 2) & 1)) * 65536u + (unsigned)wch * 16384u;
        const int off = (wch & 1) * (128 * CDIM) + (h >> 2) * 64;
        if (wch < 2) {
            gload_lds16(sB0 + off, smem + region + cbo0);
            gload_lds16(sB1 + off, smem + region + cbo1);
        } else {
            gload_lds16(sA0 + off, smem + region + cbo0);
            gload_lds16(sA1 + off, smem + region + cbo1);
        }
    };

    f32x4 acc[8][4];
#pragma unroll
    for (int i = 0; i < 8; ++i)
#pragma unroll
        for (int j = 0; j < 4; ++j) acc[i][j] = (f32x4){0.f, 0.f, 0.f, 0.f};

    // ---- prologue: stage halves 0..6 (lead 7); buffer0 (h0..h3) must land ----
    stage(0); stage(1); stage(2); stage(3); stage(4); stage(5); stage(6);
    asm volatile("s_waitcnt vmcnt(6)" ::: "memory");   // 14 outstanding -> oldest 8 (=buffer0) done
    __builtin_amdgcn_s_barrier();
    asm volatile("" ::: "memory");

#define MFMA_PHASE(Q, AF)                                                         \
    __builtin_amdgcn_s_setprio(1);                                                \
    _Pragma("unroll")                                                             \
    for (int ks = 0; ks < 2; ++ks)                                                \
        _Pragma("unroll")                                                         \
        for (int m = 0; m < 2; ++m)                                               \
            _Pragma("unroll")                                                     \
            for (int nf = 0; nf < 4; ++nf)                                        \
                acc[(Q)*2 + m][nf] = __builtin_amdgcn_mfma_f32_16x16x32_bf16(     \
                    AF[m][ks], bfr[nf][ks], acc[(Q)*2 + m][nf], 0, 0, 0);         \
    __builtin_amdgcn_s_setprio(0);

#define BARRIER() asm volatile("" ::: "memory"); __builtin_amdgcn_s_barrier(); asm volatile("" ::: "memory")

    for (int kt = 0; kt < NTILE; ++kt) {
        const char* buf = smem + ((unsigned)(kt & 1)) * 65536u;
        bf16x8 bfr[4][2], aA[2][2], aB[2][2];

        // ---------- q0: read all B + A(q0) + prefetch A(q1) ----------
#pragma unroll
        for (int nf = 0; nf < 4; ++nf) {
            bfr[nf][0] = *(const bf16x8*)(buf + boff + nf * 2048u + kx0);
            bfr[nf][1] = *(const bf16x8*)(buf + boff + nf * 2048u + kx1);
        }
#pragma unroll
        for (int m = 0; m < 2; ++m) {
            aA[m][0] = *(const bf16x8*)(buf + aoff + (0 + m) * 2048u + kx0);
            aA[m][1] = *(const bf16x8*)(buf + aoff + (0 + m) * 2048u + kx1);
        }
#pragma unroll
        for (int m = 0; m < 2; ++m) {
            aB[m][0] = *(const bf16x8*)(buf + aoff + (2 + m) * 2048u + kx0);
            aB[m][1] = *(const bf16x8*)(buf + aoff + (2 + m) * 2048u + kx1);
        }
        { int h = kt * 4 + 7; if (h < NHALF) stage(h); }
        BARRIER();
        MFMA_PHASE(0, aA);
        BARRIER();

        // ---------- q1: prefetch A(q2); MFMA with A(q1) ----------
#pragma unroll
        for (int m = 0; m < 2; ++m) {
            aA[m][0] = *(const bf16x8*)(buf + aoff + (4 + m) * 2048u + kx0);
            aA[m][1] = *(const bf16x8*)(buf + aoff + (4 + m) * 2048u + kx1);
        }
        { int h = kt * 4 + 8; if (h < NHALF) stage(h); }
        BARRIER();
        MFMA_PHASE(1, aB);
        BARRIER();

        // ---------- q2: prefetch A(q3); MFMA with A(q2) ----------
#pragma unroll
        for (int m = 0; m < 2; ++m) {
            aB[m][0] = *(const bf16x8*)(buf + aoff + (6 + m) * 2048u + kx0);
            aB[m][1] = *(const bf16x8*)(buf + aoff + (6 + m) * 2048u + kx1);
        }
        { int h = kt * 4 + 9; if (h < NHALF) stage(h); }
        BARRIER();
        MFMA_PHASE(2, aA);
        // drain q3-frag reads so q3's stage (A0 overwrite) is strictly ordered
        asm volatile("s_waitcnt lgkmcnt(0)" ::: "memory");
        BARRIER();

        // ---------- q3: MFMA with A(q3) ----------
        { int h = kt * 4 + 10; if (h < NHALF) stage(h); }
        BARRIER();
        MFMA_PHASE(3, aB);
        if (kt < NTILE - 2)       { asm volatile("s_waitcnt vmcnt(6)" ::: "memory"); }
        else if (kt == NTILE - 2) { asm volatile("s_waitcnt vmcnt(0)" ::: "memory"); }
        BARRIER();
    }
#undef MFMA_PHASE
#undef BARRIER

    // ---- epilogue: per-row (max, sum-exp, argmax) from accumulators ----
    // C/D layout: row = (lane>>4)*4 + reg, col = lane&15 (verified R1/R2).
    __syncthreads();
    float* sm = (float*)smem;            // [256][4] per-wn row max (sim units)
    float* sl = (float*)(smem + 4096);   // [256][4] sum exp
    int*   si = (int*)(smem + 8192);     // [256][4] argmax col
    const int g = lane >> 4;
#pragma unroll
    for (int mf = 0; mf < 8; ++mf) {
#pragma unroll
        for (int r = 0; r < 4; ++r) {
            const int ci = col0 + wn * 64 + (lane & 15);
            float vmax = acc[mf][0][r];
            int cbest = ci;
#pragma unroll
            for (int nf = 1; nf < 4; ++nf) {
                float v = acc[mf][nf][r];
                if (v > vmax) { vmax = v; cbest = ci + nf * 16; }
            }
#pragma unroll
            for (int m = 1; m < 16; m <<= 1) {
                float ov = __shfl_xor(vmax, m);
                int   oi = __shfl_xor(cbest, m);
                if (ov > vmax || (ov == vmax && oi < cbest)) { vmax = ov; cbest = oi; }
            }
            float s = 0.f;
#pragma unroll
            for (int nf = 0; nf < 4; ++nf)
                s += __expf((acc[mf][nf][r] - vmax) * TEMP_INV);
#pragma unroll
            for (int m = 1; m < 16; m <<= 1) s += __shfl_xor(s, m);
            if ((lane & 15) == 0) {
                int rl_ = wm * 128 + mf * 16 + g * 4 + r;
                sm[rl_ * 4 + wn] = vmax * TEMP_INV;   // sim units
                sl[rl_ * 4 + wn] = s;
                si[rl_ * 4 + wn] = cbest;
            }
        }
    }
    __syncthreads();
    if (t < 256) {
        float M = sm[t * 4];
#pragma unroll
        for (int w = 1; w < 4; ++w) M = fmaxf(M, sm[t * 4 + w]);
        float L = 0.f;
#pragma unroll
        for (int w = 0; w < 4; ++w) L += sl[t * 4 + w] * __expf(sm[t * 4 + w] - M);
        float bv = -1e30f; int bi = 0;
#pragma unroll
        for (int w = 0; w < 4; ++w) {      // ascending wn: first-index tiebreak
            float v = sm[t * 4 + w];
            if (v > bv) { bv = v; bi = si[t * 4 + w]; }
        }
        size_t o = (size_t)cb * NROW + row0 + t;
        pm[o] = M; pl[o] = L; pbi[o] = bi;
    }
}

// ---------------------------------------------------------------------------
// Kernel 3: per-row merge of 32 chunk partials + diag (from bf16 rows, fp32
// accum: error ~5e-4 logits) + loss_i/correct_i. One wave per row.
// ---------------------------------------------------------------------------
__global__ __launch_bounds__(256) void merge_kernel(
    const u16* __restrict__ xh, const u16* __restrict__ qh,
    const float* __restrict__ pm, const float* __restrict__ pl,
    const int* __restrict__ pbi,
    float* __restrict__ loss_arr, float* __restrict__ corr_arr, int n)
{
    int i    = blockIdx.x * 4 + (threadIdx.x >> 6);
    int lane = threadIdx.x & 63;
    if (i >= n) return;

    size_t base = (size_t)i * CDIM + lane * 8;
    u16x8 a = *(const u16x8*)&xh[base];
    u16x8 b = *(const u16x8*)&qh[base];
    float d = 0.f;
#pragma unroll
    for (int e = 0; e < 8; ++e) d += bf2f(a[e]) * bf2f(b[e]);
#pragma unroll
    for (int off = 32; off; off >>= 1) d += __shfl_xor(d, off);

    if (lane == 0) {
        float M = -1e30f;
        for (int c = 0; c < NCB; ++c) M = fmaxf(M, pm[(size_t)c * n + i]);
        float L = 0.f;
        for (int c = 0; c < NCB; ++c) L += pl[(size_t)c * n + i] * __expf(pm[(size_t)c * n + i] - M);
        float logZ = M + logf(L);
        float bv = -1e30f; int bi = 0;
        for (int c = 0; c < NCB; ++c) {   // ascending: lower chunk wins ties
            float v = pm[(size_t)c * n + i];
            if (v > bv) { bv = v; bi = pbi[(size_t)c * n + i]; }
        }
        loss_arr[i] = logZ - d * TEMP_INV;
        corr_arr[i] = (bi == i) ? 1.0f : 0.0f;
    }
}

// ---------------------------------------------------------------------------
// Kernel 4: deterministic single-block mean reduction -> d_out[0..1]
// ---------------------------------------------------------------------------
__global__ __launch_bounds__(256) void finalize_kernel(
    const float* __restrict__ loss_arr, const float* __restrict__ corr_arr,
    float* __restrict__ out, int n)
{
    float a = 0.f, b = 0.f;
    for (int i = threadIdx.x; i < n; i += 256) { a += loss_arr[i]; b += corr_arr[i]; }
#pragma unroll
    for (int off = 32; off; off >>= 1) { a += __shfl_xor(a, off); b += __shfl_xor(b, off); }
    __shared__ float sa[4], sb[4];
    int wid = threadIdx.x >> 6, lane = threadIdx.x & 63;
    if (lane == 0) { sa[wid] = a; sb[wid] = b; }
    __syncthreads();
    if (threadIdx.x == 0) {
        out[0] = (sa[0] + sa[1] + sa[2] + sa[3]) / n;
        out[1] = (sb[0] + sb[1] + sb[2] + sb[3]) / n;
    }
}

extern "C" void kernel_launch(void* const* d_in, const int* in_sizes, int n_in,
                              void* d_out, int out_size, void* d_ws, size_t ws_size,
                              hipStream_t stream)
{
    const float* x = (const float*)d_in[0];
    const float* q = (const float*)d_in[1];
    const int n = in_sizes[0] / CDIM;   // 8192

    char* ws = (char*)d_ws;
    size_t sz_bf = (size_t)n * CDIM * sizeof(u16);   // 8 MB each
    u16* xh = (u16*)(ws);
    u16* qh = (u16*)(ws + sz_bf);
    char* p = ws + 2 * sz_bf;
    float* pm  = (float*)p; p += (size_t)NCB * n * 4;
    float* pl  = (float*)p; p += (size_t)NCB * n * 4;
    int*   pbi = (int*)p;   p += (size_t)NCB * n * 4;
    float* loss_arr = (float*)p; p += (size_t)n * 4;
    float* corr_arr = (float*)p;

    norm_split_kernel<<<(2 * n) / 4, 256, 0, stream>>>(x, q, xh, qh, n);

    sim_main_kernel<<<(n / 256) * (n / 256), 512, 131072, stream>>>(
        xh, qh, pm, pl, pbi);

    merge_kernel<<<n / 4, 256, 0, stream>>>(xh, qh, pm, pl, pbi,
                                            loss_arr, corr_arr, n);

    finalize_kernel<<<1, 256, 0, stream>>>(loss_arr, corr_arr, (float*)d_out, n);
}

// Round 4
// 136.694 us; speedup vs baseline: 2.3319x; 1.2805x over previous
//
#include <hip/hip_runtime.h>
#include <hip/hip_bf16.h>
#include <math.h>

#define CDIM 512
#define NROW 8192
#define BM 256
#define BN 128
#define BK 32
#define NT 16              // K tiles: 512/32
#define NCB 64             // column blocks (8192/128)
#define BUFSZ 24576        // A 16 KB + B 8 KB per K-tile buffer
#define TEMP_INV 10.0f

typedef unsigned short u16;
typedef u16  u16x8 __attribute__((ext_vector_type(8)));
typedef __bf16 bf16x8 __attribute__((ext_vector_type(8)));
typedef float  f32x4 __attribute__((ext_vector_type(4)));

static __device__ __forceinline__ float bf2f(u16 u) {
    return __uint_as_float(((unsigned)u) << 16);
}
static __device__ __forceinline__ u16 f2bf(float f) {
    unsigned u = __float_as_uint(f);
    return (u16)((u + 0x7FFFu + ((u >> 16) & 1u)) >> 16);  // RNE
}

static __device__ __forceinline__ void gload_lds16(const u16* g, char* l) {
    __builtin_amdgcn_global_load_lds(
        (const __attribute__((address_space(1))) void*)g,
        (__attribute__((address_space(3))) void*)l, 16, 0, 0);
}

// ---------------------------------------------------------------------------
// Kernel 1: row-normalize (fp32 math) -> bf16 (RNE). One wave per row.
// ---------------------------------------------------------------------------
__global__ __launch_bounds__(256) void norm_split_kernel(
    const float* __restrict__ x, const float* __restrict__ q,
    u16* __restrict__ xh, u16* __restrict__ qh, int n)
{
    int wave = blockIdx.x * 4 + (threadIdx.x >> 6);
    int lane = threadIdx.x & 63;
    const float* src; u16* dh; int row;
    if (wave < n) { src = x; dh = xh; row = wave; }
    else          { src = q; dh = qh; row = wave - n; }

    const float4* p = reinterpret_cast<const float4*>(src + (size_t)row * CDIM);
    float4 a = p[lane * 2];
    float4 b = p[lane * 2 + 1];
    float v[8] = {a.x, a.y, a.z, a.w, b.x, b.y, b.z, b.w};
    float ss = 0.f;
#pragma unroll
    for (int j = 0; j < 8; ++j) ss += v[j] * v[j];
#pragma unroll
    for (int off = 32; off; off >>= 1) ss += __shfl_xor(ss, off);
    float scale = 1.0f / fmaxf(sqrtf(ss), 1e-12f);

    u16 h[8] __attribute__((aligned(16)));
#pragma unroll
    for (int j = 0; j < 8; ++j) h[j] = f2bf(v[j] * scale);
    *(u16x8*)&dh[(size_t)row * CDIM + lane * 8] = *(u16x8*)h;
}

// ---------------------------------------------------------------------------
// Kernel 2: 256x128-tile bf16 GEMM (K=512), triple-buffered BK=32, one
// barrier per K-tile, 2 blocks/CU. 8 waves (4 wm x 2 wn), wave tile 64x64.
// LDS rows are 64 B -> 16x16x32 frag reads are a 2-way bank wrap (free),
// no swizzle needed; staging dest is linear row-major.
// Fused epilogue: per-row (max, sum-exp, argmax) partials + in-tile diag,
// packed as float4 -> part[row][cb].
// ---------------------------------------------------------------------------
__global__ __launch_bounds__(512, 4) void sim_main_kernel(
    const u16* __restrict__ xh, const u16* __restrict__ qh,
    float4* __restrict__ part)
{
    extern __shared__ __align__(16) char smem[];   // 3 * 24576 = 72 KB
    const int t = threadIdx.x, lane = t & 63, wid = t >> 6;
    const int wm = wid >> 1, wn = wid & 1;

    // XCD-aware bijective swizzle (2048 % 8 == 0)
    const int orig = blockIdx.x;
    const int wg = (orig & 7) * 256 + (orig >> 3);
    const int rb = wg & 31, cb = wg >> 5;
    const int row0 = rb * BM, col0 = cb * BN;

    // staging sources (per-lane), advance by BK elems per K-tile
    const u16* sa0 = xh + (size_t)(row0 + (t >> 2)) * CDIM + (t & 3) * 8;
    const u16* sa1 = sa0 + 128 * CDIM;
    const u16* sb  = qh + (size_t)(col0 + (t >> 2)) * CDIM + (t & 3) * 8;
    const unsigned dstw = (unsigned)wid * 1024u;   // wave-uniform dest

    auto stage = [&](int kt) {
        char* b = smem + (kt % 3) * BUFSZ;
        const int ko = kt * BK;
        gload_lds16(sa0 + ko, b + dstw);
        gload_lds16(sa1 + ko, b + 8192 + dstw);
        gload_lds16(sb  + ko, b + 16384 + dstw);
    };

    // frag read offsets (row stride 64 B; lane>>4 = k-group slot)
    const unsigned aro = ((unsigned)(wm * 64 + (lane & 15))) * 64u + ((unsigned)(lane >> 4)) * 16u;
    const unsigned bro = 16384u + ((unsigned)(wn * 64 + (lane & 15))) * 64u + ((unsigned)(lane >> 4)) * 16u;

    f32x4 acc[4][4];
#pragma unroll
    for (int i = 0; i < 4; ++i)
#pragma unroll
        for (int j = 0; j < 4; ++j) acc[i][j] = (f32x4){0.f, 0.f, 0.f, 0.f};

    // prologue: lead-2
    stage(0); stage(1);
    asm volatile("s_waitcnt vmcnt(3)" ::: "memory");   // stage(0) landed
    __builtin_amdgcn_s_barrier();
    asm volatile("" ::: "memory");

    for (int kt = 0; kt < NT; ++kt) {
        const char* buf = smem + (kt % 3) * BUFSZ;
        bf16x8 afr[4], bfr[4];
#pragma unroll
        for (int mf = 0; mf < 4; ++mf) afr[mf] = *(const bf16x8*)(buf + aro + mf * 1024u);
#pragma unroll
        for (int nf = 0; nf < 4; ++nf) bfr[nf] = *(const bf16x8*)(buf + bro + nf * 1024u);
        if (kt < NT - 2) stage(kt + 2);

        __builtin_amdgcn_s_setprio(1);
#pragma unroll
        for (int mf = 0; mf < 4; ++mf)
#pragma unroll
            for (int nf = 0; nf < 4; ++nf)
                acc[mf][nf] = __builtin_amdgcn_mfma_f32_16x16x32_bf16(
                    afr[mf], bfr[nf], acc[mf][nf], 0, 0, 0);
        __builtin_amdgcn_s_setprio(0);

        if (kt < NT - 2)       { asm volatile("s_waitcnt vmcnt(3)" ::: "memory"); }
        else if (kt == NT - 2) { asm volatile("s_waitcnt vmcnt(0)" ::: "memory"); }
        // drain my ds_reads (already consumed by MFMA; ~free) so the next
        // iteration's stage into this buffer can't race them
        asm volatile("s_waitcnt lgkmcnt(0)" ::: "memory");
        __builtin_amdgcn_s_barrier();
        asm volatile("" ::: "memory");
    }

    // ---- epilogue: per-row (max, sum-exp, argmax) + in-tile diag ----
    // C/D layout: row = (lane>>4)*4 + reg, col = lane&15 (verified R1-R3).
    __syncthreads();
    float* sm = (float*)smem;              // [256][2] row max (logit units)
    float* sl = sm + 512;                  // [256][2] sum exp
    int*   si = (int*)(sl + 512);          // [256][2] argmax col
    float* sd = (float*)(si + 512);        // [256] diag (logit units)
    const int g = lane >> 4;
#pragma unroll
    for (int mf = 0; mf < 4; ++mf) {
#pragma unroll
        for (int r = 0; r < 4; ++r) {
            const int row_loc  = wm * 64 + mf * 16 + g * 4 + r;
            const int row_glob = row0 + row_loc;
            const int ci = col0 + wn * 64 + (lane & 15);
            float vmax = acc[mf][0][r];
            int cbest = ci;
#pragma unroll
            for (int nf = 1; nf < 4; ++nf) {
                float v = acc[mf][nf][r];
                if (v > vmax) { vmax = v; cbest = ci + nf * 16; }
                if (ci + nf * 16 == row_glob) sd[row_loc] = v * TEMP_INV;
            }
            if (ci == row_glob) sd[row_loc] = acc[mf][0][r] * TEMP_INV;
#pragma unroll
            for (int m = 1; m < 16; m <<= 1) {
                float ov = __shfl_xor(vmax, m);
                int   oi = __shfl_xor(cbest, m);
                if (ov > vmax || (ov == vmax && oi < cbest)) { vmax = ov; cbest = oi; }
            }
            float s = 0.f;
#pragma unroll
            for (int nf = 0; nf < 4; ++nf)
                s += __expf((acc[mf][nf][r] - vmax) * TEMP_INV);
#pragma unroll
            for (int m = 1; m < 16; m <<= 1) s += __shfl_xor(s, m);
            if ((lane & 15) == 0) {
                sm[row_loc * 2 + wn] = vmax * TEMP_INV;
                sl[row_loc * 2 + wn] = s;
                si[row_loc * 2 + wn] = cbest;
            }
        }
    }
    __syncthreads();
    if (t < 256) {
        float m0 = sm[t * 2], m1 = sm[t * 2 + 1];
        float M = fmaxf(m0, m1);
        float L = sl[t * 2] * __expf(m0 - M) + sl[t * 2 + 1] * __expf(m1 - M);
        int bi = (m1 > m0) ? si[t * 2 + 1] : si[t * 2];   // ties: lower wn (lower col) wins
        part[(size_t)(row0 + t) * NCB + cb] =
            make_float4(M, L, __int_as_float(bi), sd[t]);
    }
}

// ---------------------------------------------------------------------------
// Kernel 3: per-row merge of 64 chunk partials (coalesced float4 row) ->
// loss_i / correct_i. One wave per row; diag comes from chunk (i>>7).
// ---------------------------------------------------------------------------
__global__ __launch_bounds__(256) void merge_kernel(
    const float4* __restrict__ part,
    float* __restrict__ loss_arr, float* __restrict__ corr_arr)
{
    int i    = blockIdx.x * 4 + (threadIdx.x >> 6);
    int lane = threadIdx.x & 63;
    float4 v = part[(size_t)i * NCB + lane];

    float M = v.x;
#pragma unroll
    for (int off = 32; off; off >>= 1) M = fmaxf(M, __shfl_xor(M, off));
    float L = v.y * __expf(v.x - M);
#pragma unroll
    for (int off = 32; off; off >>= 1) L += __shfl_xor(L, off);
    float bm = v.x; int bi = __float_as_int(v.z);
#pragma unroll
    for (int off = 1; off < 64; off <<= 1) {   // first-index tiebreak
        float ov = __shfl_xor(bm, off);
        int   oi = __shfl_xor(bi, off);
        if (ov > bm || (ov == bm && oi < bi)) { bm = ov; bi = oi; }
    }
    float dg = __shfl(v.w, i >> 7);
    if (lane == 0) {
        loss_arr[i] = (M + logf(L)) - dg;
        corr_arr[i] = (bi == i) ? 1.0f : 0.0f;
    }
}

// ---------------------------------------------------------------------------
// Kernel 4: deterministic single-block mean reduction -> d_out[0..1]
// ---------------------------------------------------------------------------
__global__ __launch_bounds__(256) void finalize_kernel(
    const float* __restrict__ loss_arr, const float* __restrict__ corr_arr,
    float* __restrict__ out, int n)
{
    float a = 0.f, b = 0.f;
    for (int i = threadIdx.x; i < n; i += 256) { a += loss_arr[i]; b += corr_arr[i]; }
#pragma unroll
    for (int off = 32; off; off >>= 1) { a += __shfl_xor(a, off); b += __shfl_xor(b, off); }
    __shared__ float sa[4], sb[4];
    int wid = threadIdx.x >> 6, lane = threadIdx.x & 63;
    if (lane == 0) { sa[wid] = a; sb[wid] = b; }
    __syncthreads();
    if (threadIdx.x == 0) {
        out[0] = (sa[0] + sa[1] + sa[2] + sa[3]) / n;
        out[1] = (sb[0] + sb[1] + sb[2] + sb[3]) / n;
    }
}

extern "C" void kernel_launch(void* const* d_in, const int* in_sizes, int n_in,
                              void* d_out, int out_size, void* d_ws, size_t ws_size,
                              hipStream_t stream)
{
    const float* x = (const float*)d_in[0];
    const float* q = (const float*)d_in[1];
    const int n = in_sizes[0] / CDIM;   // 8192

    char* ws = (char*)d_ws;
    size_t sz_bf = (size_t)n * CDIM * sizeof(u16);   // 8 MB each
    u16* xh = (u16*)(ws);
    u16* qh = (u16*)(ws + sz_bf);
    char* p = ws + 2 * sz_bf;
    float4* part = (float4*)p; p += (size_t)n * NCB * sizeof(float4);  // 8 MB
    float* loss_arr = (float*)p; p += (size_t)n * 4;
    float* corr_arr = (float*)p;

    norm_split_kernel<<<(2 * n) / 4, 256, 0, stream>>>(x, q, xh, qh, n);

    sim_main_kernel<<<(n / BM) * (n / BN), 512, 3 * BUFSZ, stream>>>(xh, qh, part);

    merge_kernel<<<n / 4, 256, 0, stream>>>(part, loss_arr, corr_arr);

    finalize_kernel<<<1, 256, 0, stream>>>(loss_arr, corr_arr, (float*)d_out, n);
}

// Round 5
// 134.483 us; speedup vs baseline: 2.3702x; 1.0164x over previous
//
#include <hip/hip_runtime.h>
#include <hip/hip_bf16.h>
#include <math.h>

#define CDIM 512
#define NROW 8192
#define BM 256
#define BN 128
#define BK 32
#define NT 16              // K tiles: 512/32
#define NCB 64             // column blocks (8192/128)
#define BUFSZ 24576        // A 16 KB + B 8 KB per K-tile buffer
#define TEMP_INV 10.0f

typedef unsigned short u16;
typedef u16  u16x8 __attribute__((ext_vector_type(8)));
typedef __bf16 bf16x8 __attribute__((ext_vector_type(8)));
typedef float  f32x4 __attribute__((ext_vector_type(4)));

static __device__ __forceinline__ float bf2f(u16 u) {
    return __uint_as_float(((unsigned)u) << 16);
}
static __device__ __forceinline__ u16 f2bf(float f) {
    unsigned u = __float_as_uint(f);
    return (u16)((u + 0x7FFFu + ((u >> 16) & 1u)) >> 16);  // RNE
}

static __device__ __forceinline__ void gload_lds16(const u16* g, char* l) {
    __builtin_amdgcn_global_load_lds(
        (const __attribute__((address_space(1))) void*)g,
        (__attribute__((address_space(3))) void*)l, 16, 0, 0);
}

// ---------------------------------------------------------------------------
// Kernel 1: row-normalize (fp32 math) -> bf16 (RNE). One wave per row.
// ---------------------------------------------------------------------------
__global__ __launch_bounds__(256) void norm_split_kernel(
    const float* __restrict__ x, const float* __restrict__ q,
    u16* __restrict__ xh, u16* __restrict__ qh, int n)
{
    int wave = blockIdx.x * 4 + (threadIdx.x >> 6);
    int lane = threadIdx.x & 63;
    const float* src; u16* dh; int row;
    if (wave < n) { src = x; dh = xh; row = wave; }
    else          { src = q; dh = qh; row = wave - n; }

    const float4* p = reinterpret_cast<const float4*>(src + (size_t)row * CDIM);
    float4 a = p[lane * 2];
    float4 b = p[lane * 2 + 1];
    float v[8] = {a.x, a.y, a.z, a.w, b.x, b.y, b.z, b.w};
    float ss = 0.f;
#pragma unroll
    for (int j = 0; j < 8; ++j) ss += v[j] * v[j];
#pragma unroll
    for (int off = 32; off; off >>= 1) ss += __shfl_xor(ss, off);
    float scale = 1.0f / fmaxf(sqrtf(ss), 1e-12f);

    u16 h[8] __attribute__((aligned(16)));
#pragma unroll
    for (int j = 0; j < 8; ++j) h[j] = f2bf(v[j] * scale);
    *(u16x8*)&dh[(size_t)row * CDIM + lane * 8] = *(u16x8*)h;
}

// ---------------------------------------------------------------------------
// Kernel 2: 256x128-tile bf16 GEMM (K=512), triple-buffered BK=32, one
// barrier per K-tile, 2 blocks/CU. 8 waves (4 wm x 2 wn), wave tile 64x64.
// LDS rows are 64 B (4 chunks of 16 B). Conflict-free chunk swizzle:
//   physical_chunk = logical_chunk ^ ((row>>1)&3)
// applied on BOTH sides: stage pre-swizzles the per-lane GLOBAL source
// (LDS dest linear, as global_load_lds requires), frag reads XOR the same
// involution. Quarter-wave check: lanes 0-15 -> quads 0,16,4,20,8,24,12,28,
// repeat = 2 lanes/quad = conflict-free.
// Fused epilogue: per-row (max, sum-exp, argmax) partials + in-tile diag,
// packed as float4 -> part[row][cb].
// ---------------------------------------------------------------------------
__global__ __launch_bounds__(512, 4) void sim_main_kernel(
    const u16* __restrict__ xh, const u16* __restrict__ qh,
    float4* __restrict__ part)
{
    extern __shared__ __align__(16) char smem[];   // 3 * 24576 = 72 KB
    const int t = threadIdx.x, lane = t & 63, wid = t >> 6;
    const int wm = wid >> 1, wn = wid & 1;

    // XCD-aware bijective swizzle (2048 % 8 == 0)
    const int orig = blockIdx.x;
    const int wg = (orig & 7) * 256 + (orig >> 3);
    const int rb = wg & 31, cb = wg >> 5;
    const int row0 = rb * BM, col0 = cb * BN;

    // staging sources (per-lane), advance by BK elems per K-tile.
    // thread t fills LDS row (t>>2), physical chunk (t&3); the global
    // chunk it must carry is (t&3) ^ ((row>>1)&3) = (t&3) ^ ((t>>3)&3).
    const int schunk = (t & 3) ^ ((t >> 3) & 3);
    const u16* sa0 = xh + (size_t)(row0 + (t >> 2)) * CDIM + schunk * 8;
    const u16* sa1 = sa0 + 128 * CDIM;
    const u16* sb  = qh + (size_t)(col0 + (t >> 2)) * CDIM + schunk * 8;
    const unsigned dstw = (unsigned)wid * 1024u;   // wave-uniform dest

    auto stage = [&](int kt) {
        char* b = smem + (kt % 3) * BUFSZ;
        const int ko = kt * BK;
        gload_lds16(sa0 + ko, b + dstw);
        gload_lds16(sa1 + ko, b + 8192 + dstw);
        gload_lds16(sb  + ko, b + 16384 + dstw);
    };

    // frag read offsets (row stride 64 B); logical k-slot = lane>>4,
    // physical chunk = (lane>>4) ^ ((row>>1)&3), row bits 1-2 = lane bits 1-2
    const unsigned kxc = ((unsigned)((lane >> 4) ^ ((lane >> 1) & 3))) * 16u;
    const unsigned aro = ((unsigned)(wm * 64 + (lane & 15))) * 64u + kxc;
    const unsigned bro = 16384u + ((unsigned)(wn * 64 + (lane & 15))) * 64u + kxc;

    f32x4 acc[4][4];
#pragma unroll
    for (int i = 0; i < 4; ++i)
#pragma unroll
        for (int j = 0; j < 4; ++j) acc[i][j] = (f32x4){0.f, 0.f, 0.f, 0.f};

    // prologue: lead-2
    stage(0); stage(1);
    asm volatile("s_waitcnt vmcnt(3)" ::: "memory");   // stage(0) landed
    __builtin_amdgcn_s_barrier();
    asm volatile("" ::: "memory");

    for (int kt = 0; kt < NT; ++kt) {
        const char* buf = smem + (kt % 3) * BUFSZ;
        // issue next-next stage FIRST (T3 ordering: loads fly during reads+MFMA)
        if (kt < NT - 2) stage(kt + 2);
        bf16x8 afr[4], bfr[4];
#pragma unroll
        for (int mf = 0; mf < 4; ++mf) afr[mf] = *(const bf16x8*)(buf + aro + mf * 1024u);
#pragma unroll
        for (int nf = 0; nf < 4; ++nf) bfr[nf] = *(const bf16x8*)(buf + bro + nf * 1024u);

        __builtin_amdgcn_s_setprio(1);
#pragma unroll
        for (int mf = 0; mf < 4; ++mf)
#pragma unroll
            for (int nf = 0; nf < 4; ++nf)
                acc[mf][nf] = __builtin_amdgcn_mfma_f32_16x16x32_bf16(
                    afr[mf], bfr[nf], acc[mf][nf], 0, 0, 0);
        __builtin_amdgcn_s_setprio(0);

        if (kt < NT - 2)       { asm volatile("s_waitcnt vmcnt(3)" ::: "memory"); }
        else if (kt == NT - 2) { asm volatile("s_waitcnt vmcnt(0)" ::: "memory"); }
        // my ds_reads are already consumed by MFMA (compiler-counted lgkm),
        // so this is ~free; keeps buffer-reuse ordering explicit
        asm volatile("s_waitcnt lgkmcnt(0)" ::: "memory");
        __builtin_amdgcn_s_barrier();
        asm volatile("" ::: "memory");
    }

    // ---- epilogue: per-row (max, sum-exp, argmax) + in-tile diag ----
    // C/D layout: row = (lane>>4)*4 + reg, col = lane&15 (verified R1-R4).
    __syncthreads();
    float* sm = (float*)smem;              // [256][2] row max (logit units)
    float* sl = sm + 512;                  // [256][2] sum exp
    int*   si = (int*)(sl + 512);          // [256][2] argmax col
    float* sd = (float*)(si + 512);        // [256] diag (logit units)
    const int g = lane >> 4;
#pragma unroll
    for (int mf = 0; mf < 4; ++mf) {
#pragma unroll
        for (int r = 0; r < 4; ++r) {
            const int row_loc  = wm * 64 + mf * 16 + g * 4 + r;
            const int row_glob = row0 + row_loc;
            const int ci = col0 + wn * 64 + (lane & 15);
            float vmax = acc[mf][0][r];
            int cbest = ci;
#pragma unroll
            for (int nf = 1; nf < 4; ++nf) {
                float v = acc[mf][nf][r];
                if (v > vmax) { vmax = v; cbest = ci + nf * 16; }
                if (ci + nf * 16 == row_glob) sd[row_loc] = v * TEMP_INV;
            }
            if (ci == row_glob) sd[row_loc] = acc[mf][0][r] * TEMP_INV;
#pragma unroll
            for (int m = 1; m < 16; m <<= 1) {
                float ov = __shfl_xor(vmax, m);
                int   oi = __shfl_xor(cbest, m);
                if (ov > vmax || (ov == vmax && oi < cbest)) { vmax = ov; cbest = oi; }
            }
            float s = 0.f;
#pragma unroll
            for (int nf = 0; nf < 4; ++nf)
                s += __expf((acc[mf][nf][r] - vmax) * TEMP_INV);
#pragma unroll
            for (int m = 1; m < 16; m <<= 1) s += __shfl_xor(s, m);
            if ((lane & 15) == 0) {
                sm[row_loc * 2 + wn] = vmax * TEMP_INV;
                sl[row_loc * 2 + wn] = s;
                si[row_loc * 2 + wn] = cbest;
            }
        }
    }
    __syncthreads();
    if (t < 256) {
        float m0 = sm[t * 2], m1 = sm[t * 2 + 1];
        float M = fmaxf(m0, m1);
        float L = sl[t * 2] * __expf(m0 - M) + sl[t * 2 + 1] * __expf(m1 - M);
        int bi = (m1 > m0) ? si[t * 2 + 1] : si[t * 2];   // ties: lower wn (lower col) wins
        part[(size_t)(row0 + t) * NCB + cb] =
            make_float4(M, L, __int_as_float(bi), sd[t]);
    }
}

// ---------------------------------------------------------------------------
// Kernel 3: per-row merge of 64 chunk partials (coalesced float4 row) ->
// loss_i / correct_i. One wave per row; diag comes from chunk (i>>7).
// ---------------------------------------------------------------------------
__global__ __launch_bounds__(256) void merge_kernel(
    const float4* __restrict__ part,
    float* __restrict__ loss_arr, float* __restrict__ corr_arr)
{
    int i    = blockIdx.x * 4 + (threadIdx.x >> 6);
    int lane = threadIdx.x & 63;
    float4 v = part[(size_t)i * NCB + lane];

    float M = v.x;
#pragma unroll
    for (int off = 32; off; off >>= 1) M = fmaxf(M, __shfl_xor(M, off));
    float L = v.y * __expf(v.x - M);
#pragma unroll
    for (int off = 32; off; off >>= 1) L += __shfl_xor(L, off);
    float bm = v.x; int bi = __float_as_int(v.z);
#pragma unroll
    for (int off = 1; off < 64; off <<= 1) {   // first-index tiebreak
        float ov = __shfl_xor(bm, off);
        int   oi = __shfl_xor(bi, off);
        if (ov > bm || (ov == bm && oi < bi)) { bm = ov; bi = oi; }
    }
    float dg = __shfl(v.w, i >> 7);
    if (lane == 0) {
        loss_arr[i] = (M + logf(L)) - dg;
        corr_arr[i] = (bi == i) ? 1.0f : 0.0f;
    }
}

// ---------------------------------------------------------------------------
// Kernel 4: deterministic single-block mean reduction -> d_out[0..1]
// ---------------------------------------------------------------------------
__global__ __launch_bounds__(256) void finalize_kernel(
    const float* __restrict__ loss_arr, const float* __restrict__ corr_arr,
    float* __restrict__ out, int n)
{
    float a = 0.f, b = 0.f;
    for (int i = threadIdx.x; i < n; i += 256) { a += loss_arr[i]; b += corr_arr[i]; }
#pragma unroll
    for (int off = 32; off; off >>= 1) { a += __shfl_xor(a, off); b += __shfl_xor(b, off); }
    __shared__ float sa[4], sb[4];
    int wid = threadIdx.x >> 6, lane = threadIdx.x & 63;
    if (lane == 0) { sa[wid] = a; sb[wid] = b; }
    __syncthreads();
    if (threadIdx.x == 0) {
        out[0] = (sa[0] + sa[1] + sa[2] + sa[3]) / n;
        out[1] = (sb[0] + sb[1] + sb[2] + sb[3]) / n;
    }
}

extern "C" void kernel_launch(void* const* d_in, const int* in_sizes, int n_in,
                              void* d_out, int out_size, void* d_ws, size_t ws_size,
                              hipStream_t stream)
{
    const float* x = (const float*)d_in[0];
    const float* q = (const float*)d_in[1];
    const int n = in_sizes[0] / CDIM;   // 8192

    char* ws = (char*)d_ws;
    size_t sz_bf = (size_t)n * CDIM * sizeof(u16);   // 8 MB each
    u16* xh = (u16*)(ws);
    u16* qh = (u16*)(ws + sz_bf);
    char* p = ws + 2 * sz_bf;
    float4* part = (float4*)p; p += (size_t)n * NCB * sizeof(float4);  // 8 MB
    float* loss_arr = (float*)p; p += (size_t)n * 4;
    float* corr_arr = (float*)p;

    norm_split_kernel<<<(2 * n) / 4, 256, 0, stream>>>(x, q, xh, qh, n);

    sim_main_kernel<<<(n / BM) * (n / BN), 512, 3 * BUFSZ, stream>>>(xh, qh, part);

    merge_kernel<<<n / 4, 256, 0, stream>>>(part, loss_arr, corr_arr);

    finalize_kernel<<<1, 256, 0, stream>>>(loss_arr, corr_arr, (float*)d_out, n);
}

// Round 6
// 122.852 us; speedup vs baseline: 2.5946x; 1.0947x over previous
//
#include <hip/hip_runtime.h>
#include <hip/hip_bf16.h>
#include <math.h>

#define CDIM 512
#define NROW 8192
#define BM 256
#define BN 256
#define BK 32
#define NT 16              // K tiles: 512/32
#define NCB 32             // column blocks (8192/256)
#define BUFSZ 32768        // A 16 KB + B 16 KB per K-tile buffer
#define TEMP_INV 10.0f

typedef unsigned short u16;
typedef u16  u16x8 __attribute__((ext_vector_type(8)));
typedef __bf16 bf16x8 __attribute__((ext_vector_type(8)));
typedef float  f32x4 __attribute__((ext_vector_type(4)));

static __device__ __forceinline__ float bf2f(u16 u) {
    return __uint_as_float(((unsigned)u) << 16);
}
static __device__ __forceinline__ u16 f2bf(float f) {
    unsigned u = __float_as_uint(f);
    return (u16)((u + 0x7FFFu + ((u >> 16) & 1u)) >> 16);  // RNE
}

static __device__ __forceinline__ void gload_lds16(const u16* g, char* l) {
    __builtin_amdgcn_global_load_lds(
        (const __attribute__((address_space(1))) void*)g,
        (__attribute__((address_space(3))) void*)l, 16, 0, 0);
}

// ---------------------------------------------------------------------------
// Kernel 1: row-normalize (fp32 math) -> bf16 (RNE). One wave per row.
// ---------------------------------------------------------------------------
__global__ __launch_bounds__(256) void norm_split_kernel(
    const float* __restrict__ x, const float* __restrict__ q,
    u16* __restrict__ xh, u16* __restrict__ qh, int n)
{
    int wave = blockIdx.x * 4 + (threadIdx.x >> 6);
    int lane = threadIdx.x & 63;
    const float* src; u16* dh; int row;
    if (wave < n) { src = x; dh = xh; row = wave; }
    else          { src = q; dh = qh; row = wave - n; }

    const float4* p = reinterpret_cast<const float4*>(src + (size_t)row * CDIM);
    float4 a = p[lane * 2];
    float4 b = p[lane * 2 + 1];
    float v[8] = {a.x, a.y, a.z, a.w, b.x, b.y, b.z, b.w};
    float ss = 0.f;
#pragma unroll
    for (int j = 0; j < 8; ++j) ss += v[j] * v[j];
#pragma unroll
    for (int off = 32; off; off >>= 1) ss += __shfl_xor(ss, off);
    float scale = 1.0f / fmaxf(sqrtf(ss), 1e-12f);

    u16 h[8] __attribute__((aligned(16)));
#pragma unroll
    for (int j = 0; j < 8; ++j) h[j] = f2bf(v[j] * scale);
    *(u16x8*)&dh[(size_t)row * CDIM + lane * 8] = *(u16x8*)h;
}

// ---------------------------------------------------------------------------
// Kernel 2: 256x256-tile bf16 GEMM (K=512), triple-buffered BK=32, one
// barrier per K-tile. 1024 threads = 16 waves (4 wm x 4 wn), wave tile 64x64
// (identical per-wave pattern to R5: conflict-verified chunk swizzle
// physical_chunk = logical_chunk ^ ((row>>1)&3), applied on both sides).
// XCD blocking: xcd = orig&7 owns all 32 rb x 4 cb, rb-outer order ->
// co-resident L2 footprint/XCD = 8 A-panels (2MB) + 4 B-panels (1MB) = 3MB.
// Fused epilogue: per-row (max, sum-exp, argmax) partials + in-tile diag
// (diag tile iff rb==cb), packed float4 -> part[row][cb].
// ---------------------------------------------------------------------------
__global__ __launch_bounds__(1024, 4) void sim_main_kernel(
    const u16* __restrict__ xh, const u16* __restrict__ qh,
    float4* __restrict__ part)
{
    extern __shared__ __align__(16) char smem[];   // 3 * 32768 = 96 KB
    const int t = threadIdx.x, lane = t & 63, wid = t >> 6;
    const int wm = wid >> 2, wn = wid & 3;

    // XCD-resident blocking: orig&7 = XCD (hw round-robin), rb outer, cb inner
    const int orig = blockIdx.x;
    const int xcd = orig & 7, s = orig >> 3;       // s in [0,128)
    const int rb = s >> 2;                          // 0..31
    const int cb = xcd * 4 + (s & 3);               // 0..31
    const int row0 = rb * BM, col0 = cb * BN;

    // staging sources (per-lane): thread t fills LDS row (t>>2), physical
    // chunk (t&3); global chunk = (t&3) ^ ((row>>1)&3) = (t&3) ^ ((t>>3)&3)
    const int schunk = (t & 3) ^ ((t >> 3) & 3);
    const u16* sa = xh + (size_t)(row0 + (t >> 2)) * CDIM + schunk * 8;
    const u16* sb = qh + (size_t)(col0 + (t >> 2)) * CDIM + schunk * 8;
    const unsigned dstw = (unsigned)wid * 1024u;   // wave-uniform dest

    auto stage = [&](int kt) {
        char* b = smem + (kt % 3) * BUFSZ;
        const int ko = kt * BK;
        gload_lds16(sa + ko, b + dstw);             // A: rows 0..255 x 32k
        gload_lds16(sb + ko, b + 16384 + dstw);     // B: rows 0..255 x 32k
    };

    // frag read offsets (row stride 64 B); physical chunk = slot ^ ((row>>1)&3)
    const unsigned kxc = ((unsigned)((lane >> 4) ^ ((lane >> 1) & 3))) * 16u;
    const unsigned aro = ((unsigned)(wm * 64 + (lane & 15))) * 64u + kxc;
    const unsigned bro = 16384u + ((unsigned)(wn * 64 + (lane & 15))) * 64u + kxc;

    f32x4 acc[4][4];
#pragma unroll
    for (int i = 0; i < 4; ++i)
#pragma unroll
        for (int j = 0; j < 4; ++j) acc[i][j] = (f32x4){0.f, 0.f, 0.f, 0.f};

    // prologue: lead-2
    stage(0); stage(1);
    asm volatile("s_waitcnt vmcnt(2)" ::: "memory");   // stage(0) landed
    __builtin_amdgcn_s_barrier();
    asm volatile("" ::: "memory");

    for (int kt = 0; kt < NT; ++kt) {
        const char* buf = smem + (kt % 3) * BUFSZ;
        // issue next-next stage FIRST (loads fly during reads+MFMA)
        if (kt < NT - 2) stage(kt + 2);
        bf16x8 afr[4], bfr[4];
#pragma unroll
        for (int mf = 0; mf < 4; ++mf) afr[mf] = *(const bf16x8*)(buf + aro + mf * 1024u);
#pragma unroll
        for (int nf = 0; nf < 4; ++nf) bfr[nf] = *(const bf16x8*)(buf + bro + nf * 1024u);

        __builtin_amdgcn_s_setprio(1);
#pragma unroll
        for (int mf = 0; mf < 4; ++mf)
#pragma unroll
            for (int nf = 0; nf < 4; ++nf)
                acc[mf][nf] = __builtin_amdgcn_mfma_f32_16x16x32_bf16(
                    afr[mf], bfr[nf], acc[mf][nf], 0, 0, 0);
        __builtin_amdgcn_s_setprio(0);

        if (kt < NT - 2)       { asm volatile("s_waitcnt vmcnt(2)" ::: "memory"); }
        else if (kt == NT - 2) { asm volatile("s_waitcnt vmcnt(0)" ::: "memory"); }
        // reads of buf[kt%3] must complete before kt+1 stages into it (kt+3%3)
        asm volatile("s_waitcnt lgkmcnt(0)" ::: "memory");
        __builtin_amdgcn_s_barrier();
        asm volatile("" ::: "memory");
    }

    // ---- epilogue: per-row (max, sum-exp, argmax) + in-tile diag ----
    // C/D layout: row = (lane>>4)*4 + reg, col = lane&15 (verified R1-R5).
    __syncthreads();
    float* sm = (float*)smem;              // [256][4] row max (logit units)
    float* sl = sm + 1024;                 // [256][4] sum exp
    int*   si = (int*)(sl + 1024);         // [256][4] argmax col
    float* sd = (float*)(si + 1024);       // [256] diag (logit units)
    const int g = lane >> 4;
#pragma unroll
    for (int mf = 0; mf < 4; ++mf) {
#pragma unroll
        for (int r = 0; r < 4; ++r) {
            const int row_loc  = wm * 64 + mf * 16 + g * 4 + r;
            const int row_glob = row0 + row_loc;
            const int ci = col0 + wn * 64 + (lane & 15);
            float vmax = acc[mf][0][r];
            int cbest = ci;
#pragma unroll
            for (int nf = 1; nf < 4; ++nf) {
                float v = acc[mf][nf][r];
                if (v > vmax) { vmax = v; cbest = ci + nf * 16; }
                if (ci + nf * 16 == row_glob) sd[row_loc] = v * TEMP_INV;
            }
            if (ci == row_glob) sd[row_loc] = acc[mf][0][r] * TEMP_INV;
#pragma unroll
            for (int m = 1; m < 16; m <<= 1) {
                float ov = __shfl_xor(vmax, m);
                int   oi = __shfl_xor(cbest, m);
                if (ov > vmax || (ov == vmax && oi < cbest)) { vmax = ov; cbest = oi; }
            }
            float ssum = 0.f;
#pragma unroll
            for (int nf = 0; nf < 4; ++nf)
                ssum += __expf((acc[mf][nf][r] - vmax) * TEMP_INV);
#pragma unroll
            for (int m = 1; m < 16; m <<= 1) ssum += __shfl_xor(ssum, m);
            if ((lane & 15) == 0) {
                sm[row_loc * 4 + wn] = vmax * TEMP_INV;
                sl[row_loc * 4 + wn] = ssum;
                si[row_loc * 4 + wn] = cbest;
            }
        }
    }
    __syncthreads();
    if (t < 256) {
        float M = sm[t * 4];
#pragma unroll
        for (int w = 1; w < 4; ++w) M = fmaxf(M, sm[t * 4 + w]);
        float L = 0.f;
#pragma unroll
        for (int w = 0; w < 4; ++w) L += sl[t * 4 + w] * __expf(sm[t * 4 + w] - M);
        float bv = -1e30f; int bi = 0;
#pragma unroll
        for (int w = 0; w < 4; ++w) {      // ascending wn: first-index tiebreak
            float v = sm[t * 4 + w];
            if (v > bv) { bv = v; bi = si[t * 4 + w]; }
        }
        part[(size_t)(row0 + t) * NCB + cb] =
            make_float4(M, L, __int_as_float(bi), sd[t]);
    }
}

// ---------------------------------------------------------------------------
// Kernel 3: per-row merge of 32 chunk partials -> loss_i / correct_i.
// One wave per row; lanes>=32 hold duplicates (zeroed for the sum).
// Diag comes from chunk (i>>8).
// ---------------------------------------------------------------------------
__global__ __launch_bounds__(256) void merge_kernel(
    const float4* __restrict__ part,
    float* __restrict__ loss_arr, float* __restrict__ corr_arr)
{
    int i    = blockIdx.x * 4 + (threadIdx.x >> 6);
    int lane = threadIdx.x & 63;
    float4 v = part[(size_t)i * NCB + (lane & 31)];

    float M = v.x;
#pragma unroll
    for (int off = 32; off; off >>= 1) M = fmaxf(M, __shfl_xor(M, off));
    float L = (lane < 32) ? v.y * __expf(v.x - M) : 0.f;
#pragma unroll
    for (int off = 32; off; off >>= 1) L += __shfl_xor(L, off);
    float bm = v.x; int bi = __float_as_int(v.z);
#pragma unroll
    for (int off = 1; off < 32; off <<= 1) {   // first-index tiebreak
        float ov = __shfl_xor(bm, off);
        int   oi = __shfl_xor(bi, off);
        if (ov > bm || (ov == bm && oi < bi)) { bm = ov; bi = oi; }
    }
    float dg = __shfl(v.w, i >> 8);
    if (lane == 0) {
        loss_arr[i] = (M + logf(L)) - dg;
        corr_arr[i] = (bi == i) ? 1.0f : 0.0f;
    }
}

// ---------------------------------------------------------------------------
// Kernel 4: deterministic single-block mean reduction -> d_out[0..1]
// ---------------------------------------------------------------------------
__global__ __launch_bounds__(256) void finalize_kernel(
    const float* __restrict__ loss_arr, const float* __restrict__ corr_arr,
    float* __restrict__ out, int n)
{
    float a = 0.f, b = 0.f;
    for (int i = threadIdx.x; i < n; i += 256) { a += loss_arr[i]; b += corr_arr[i]; }
#pragma unroll
    for (int off = 32; off; off >>= 1) { a += __shfl_xor(a, off); b += __shfl_xor(b, off); }
    __shared__ float sa[4], sb[4];
    int wid = threadIdx.x >> 6, lane = threadIdx.x & 63;
    if (lane == 0) { sa[wid] = a; sb[wid] = b; }
    __syncthreads();
    if (threadIdx.x == 0) {
        out[0] = (sa[0] + sa[1] + sa[2] + sa[3]) / n;
        out[1] = (sb[0] + sb[1] + sb[2] + sb[3]) / n;
    }
}

extern "C" void kernel_launch(void* const* d_in, const int* in_sizes, int n_in,
                              void* d_out, int out_size, void* d_ws, size_t ws_size,
                              hipStream_t stream)
{
    const float* x = (const float*)d_in[0];
    const float* q = (const float*)d_in[1];
    const int n = in_sizes[0] / CDIM;   // 8192

    char* ws = (char*)d_ws;
    size_t sz_bf = (size_t)n * CDIM * sizeof(u16);   // 8 MB each
    u16* xh = (u16*)(ws);
    u16* qh = (u16*)(ws + sz_bf);
    char* p = ws + 2 * sz_bf;
    float4* part = (float4*)p; p += (size_t)n * NCB * sizeof(float4);  // 4 MB
    float* loss_arr = (float*)p; p += (size_t)n * 4;
    float* corr_arr = (float*)p;

    norm_split_kernel<<<(2 * n) / 4, 256, 0, stream>>>(x, q, xh, qh, n);

    sim_main_kernel<<<(n / BM) * (n / BN), 1024, 3 * BUFSZ, stream>>>(xh, qh, part);

    merge_kernel<<<n / 4, 256, 0, stream>>>(part, loss_arr, corr_arr);

    finalize_kernel<<<1, 256, 0, stream>>>(loss_arr, corr_arr, (float*)d_out, n);
}

// Round 7
// 122.604 us; speedup vs baseline: 2.5998x; 1.0020x over previous
//
#include <hip/hip_runtime.h>
#include <hip/hip_bf16.h>
#include <math.h>

#define CDIM 512
#define NROW 8192
#define BM 256
#define BN 256
#define BK 32
#define NT 16              // K tiles: 512/32
#define NCB 32             // column blocks (8192/256)
#define BUFSZ 32768        // A 16 KB + B 16 KB per K-tile buffer
#define TEMP_INV 10.0f

typedef unsigned short u16;
typedef u16  u16x8 __attribute__((ext_vector_type(8)));
typedef __bf16 bf16x8 __attribute__((ext_vector_type(8)));
typedef float  f32x4 __attribute__((ext_vector_type(4)));

static __device__ __forceinline__ float bf2f(u16 u) {
    return __uint_as_float(((unsigned)u) << 16);
}
static __device__ __forceinline__ u16 f2bf(float f) {
    unsigned u = __float_as_uint(f);
    return (u16)((u + 0x7FFFu + ((u >> 16) & 1u)) >> 16);  // RNE
}

static __device__ __forceinline__ void gload_lds16(const u16* g, char* l) {
    __builtin_amdgcn_global_load_lds(
        (const __attribute__((address_space(1))) void*)g,
        (__attribute__((address_space(3))) void*)l, 16, 0, 0);
}

// ---------------------------------------------------------------------------
// Kernel 1: row-normalize (fp32 math) -> bf16 (RNE). One wave per row.
// ---------------------------------------------------------------------------
__global__ __launch_bounds__(256) void norm_split_kernel(
    const float* __restrict__ x, const float* __restrict__ q,
    u16* __restrict__ xh, u16* __restrict__ qh, int n)
{
    int wave = blockIdx.x * 4 + (threadIdx.x >> 6);
    int lane = threadIdx.x & 63;
    const float* src; u16* dh; int row;
    if (wave < n) { src = x; dh = xh; row = wave; }
    else          { src = q; dh = qh; row = wave - n; }

    const float4* p = reinterpret_cast<const float4*>(src + (size_t)row * CDIM);
    float4 a = p[lane * 2];
    float4 b = p[lane * 2 + 1];
    float v[8] = {a.x, a.y, a.z, a.w, b.x, b.y, b.z, b.w};
    float ss = 0.f;
#pragma unroll
    for (int j = 0; j < 8; ++j) ss += v[j] * v[j];
#pragma unroll
    for (int off = 32; off; off >>= 1) ss += __shfl_xor(ss, off);
    float scale = 1.0f / fmaxf(sqrtf(ss), 1e-12f);

    u16 h[8] __attribute__((aligned(16)));
#pragma unroll
    for (int j = 0; j < 8; ++j) h[j] = f2bf(v[j] * scale);
    *(u16x8*)&dh[(size_t)row * CDIM + lane * 8] = *(u16x8*)h;
}

// ---------------------------------------------------------------------------
// Kernel 2: 256x256-tile bf16 GEMM (K=512), triple-buffered BK=32, one
// barrier per K-tile. 1024 threads = 16 waves (4 wm x 4 wn), wave tile 64x64
// (identical per-wave pattern to R5: conflict-verified chunk swizzle
// physical_chunk = logical_chunk ^ ((row>>1)&3), applied on both sides).
// XCD blocking: xcd = orig&7 owns all 32 rb x 4 cb, rb-outer order ->
// co-resident L2 footprint/XCD = 8 A-panels (2MB) + 4 B-panels (1MB) = 3MB.
// Fused epilogue: per-row (max, sum-exp, argmax) partials + in-tile diag
// (diag tile iff rb==cb), packed float4 -> part[row][cb].
// ---------------------------------------------------------------------------
__global__ __launch_bounds__(1024, 4) void sim_main_kernel(
    const u16* __restrict__ xh, const u16* __restrict__ qh,
    float4* __restrict__ part)
{
    extern __shared__ __align__(16) char smem[];   // 3 * 32768 = 96 KB
    const int t = threadIdx.x, lane = t & 63, wid = t >> 6;
    const int wm = wid >> 2, wn = wid & 3;

    // XCD-resident blocking: orig&7 = XCD (hw round-robin), rb outer, cb inner
    const int orig = blockIdx.x;
    const int xcd = orig & 7, s = orig >> 3;       // s in [0,128)
    const int rb = s >> 2;                          // 0..31
    const int cb = xcd * 4 + (s & 3);               // 0..31
    const int row0 = rb * BM, col0 = cb * BN;

    // staging sources (per-lane): thread t fills LDS row (t>>2), physical
    // chunk (t&3); global chunk = (t&3) ^ ((row>>1)&3) = (t&3) ^ ((t>>3)&3)
    const int schunk = (t & 3) ^ ((t >> 3) & 3);
    const u16* sa = xh + (size_t)(row0 + (t >> 2)) * CDIM + schunk * 8;
    const u16* sb = qh + (size_t)(col0 + (t >> 2)) * CDIM + schunk * 8;
    const unsigned dstw = (unsigned)wid * 1024u;   // wave-uniform dest

    auto stage = [&](int kt) {
        char* b = smem + (kt % 3) * BUFSZ;
        const int ko = kt * BK;
        gload_lds16(sa + ko, b + dstw);             // A: rows 0..255 x 32k
        gload_lds16(sb + ko, b + 16384 + dstw);     // B: rows 0..255 x 32k
    };

    // frag read offsets (row stride 64 B); physical chunk = slot ^ ((row>>1)&3)
    const unsigned kxc = ((unsigned)((lane >> 4) ^ ((lane >> 1) & 3))) * 16u;
    const unsigned aro = ((unsigned)(wm * 64 + (lane & 15))) * 64u + kxc;
    const unsigned bro = 16384u + ((unsigned)(wn * 64 + (lane & 15))) * 64u + kxc;

    f32x4 acc[4][4];
#pragma unroll
    for (int i = 0; i < 4; ++i)
#pragma unroll
        for (int j = 0; j < 4; ++j) acc[i][j] = (f32x4){0.f, 0.f, 0.f, 0.f};

    // prologue: lead-2
    stage(0); stage(1);
    asm volatile("s_waitcnt vmcnt(2)" ::: "memory");   // stage(0) landed
    __builtin_amdgcn_s_barrier();
    asm volatile("" ::: "memory");

    for (int kt = 0; kt < NT; ++kt) {
        const char* buf = smem + (kt % 3) * BUFSZ;
        // issue next-next stage FIRST (loads fly during reads+MFMA)
        if (kt < NT - 2) stage(kt + 2);
        bf16x8 afr[4], bfr[4];
#pragma unroll
        for (int mf = 0; mf < 4; ++mf) afr[mf] = *(const bf16x8*)(buf + aro + mf * 1024u);
#pragma unroll
        for (int nf = 0; nf < 4; ++nf) bfr[nf] = *(const bf16x8*)(buf + bro + nf * 1024u);

        __builtin_amdgcn_s_setprio(1);
#pragma unroll
        for (int mf = 0; mf < 4; ++mf)
#pragma unroll
            for (int nf = 0; nf < 4; ++nf)
                acc[mf][nf] = __builtin_amdgcn_mfma_f32_16x16x32_bf16(
                    afr[mf], bfr[nf], acc[mf][nf], 0, 0, 0);
        __builtin_amdgcn_s_setprio(0);

        if (kt < NT - 2)       { asm volatile("s_waitcnt vmcnt(2)" ::: "memory"); }
        else if (kt == NT - 2) { asm volatile("s_waitcnt vmcnt(0)" ::: "memory"); }
        // reads of buf[kt%3] must complete before kt+1 stages into it (kt+3%3)
        asm volatile("s_waitcnt lgkmcnt(0)" ::: "memory");
        __builtin_amdgcn_s_barrier();
        asm volatile("" ::: "memory");
    }

    // ---- epilogue: per-row (max, sum-exp, argmax) + in-tile diag ----
    // C/D layout: row = (lane>>4)*4 + reg, col = lane&15 (verified R1-R5).
    __syncthreads();
    float* sm = (float*)smem;              // [256][4] row max (logit units)
    float* sl = sm + 1024;                 // [256][4] sum exp
    int*   si = (int*)(sl + 1024);         // [256][4] argmax col
    float* sd = (float*)(si + 1024);       // [256] diag (logit units)
    const int g = lane >> 4;
#pragma unroll
    for (int mf = 0; mf < 4; ++mf) {
#pragma unroll
        for (int r = 0; r < 4; ++r) {
            const int row_loc  = wm * 64 + mf * 16 + g * 4 + r;
            const int row_glob = row0 + row_loc;
            const int ci = col0 + wn * 64 + (lane & 15);
            float vmax = acc[mf][0][r];
            int cbest = ci;
#pragma unroll
            for (int nf = 1; nf < 4; ++nf) {
                float v = acc[mf][nf][r];
                if (v > vmax) { vmax = v; cbest = ci + nf * 16; }
                if (ci + nf * 16 == row_glob) sd[row_loc] = v * TEMP_INV;
            }
            if (ci == row_glob) sd[row_loc] = acc[mf][0][r] * TEMP_INV;
#pragma unroll
            for (int m = 1; m < 16; m <<= 1) {
                float ov = __shfl_xor(vmax, m);
                int   oi = __shfl_xor(cbest, m);
                if (ov > vmax || (ov == vmax && oi < cbest)) { vmax = ov; cbest = oi; }
            }
            float ssum = 0.f;
#pragma unroll
            for (int nf = 0; nf < 4; ++nf)
                ssum += __expf((acc[mf][nf][r] - vmax) * TEMP_INV);
#pragma unroll
            for (int m = 1; m < 16; m <<= 1) ssum += __shfl_xor(ssum, m);
            if ((lane & 15) == 0) {
                sm[row_loc * 4 + wn] = vmax * TEMP_INV;
                sl[row_loc * 4 + wn] = ssum;
                si[row_loc * 4 + wn] = cbest;
            }
        }
    }
    __syncthreads();
    if (t < 256) {
        float M = sm[t * 4];
#pragma unroll
        for (int w = 1; w < 4; ++w) M = fmaxf(M, sm[t * 4 + w]);
        float L = 0.f;
#pragma unroll
        for (int w = 0; w < 4; ++w) L += sl[t * 4 + w] * __expf(sm[t * 4 + w] - M);
        float bv = -1e30f; int bi = 0;
#pragma unroll
        for (int w = 0; w < 4; ++w) {      // ascending wn: first-index tiebreak
            float v = sm[t * 4 + w];
            if (v > bv) { bv = v; bi = si[t * 4 + w]; }
        }
        part[(size_t)(row0 + t) * NCB + cb] =
            make_float4(M, L, __int_as_float(bi), sd[t]);
    }
}

// ---------------------------------------------------------------------------
// Kernel 3: per-row merge of 32 chunk partials -> loss_i / correct_i.
// One wave per row; lanes>=32 hold duplicates (zeroed for the sum).
// Diag comes from chunk (i>>8).
// ---------------------------------------------------------------------------
__global__ __launch_bounds__(256) void merge_kernel(
    const float4* __restrict__ part,
    float* __restrict__ loss_arr, float* __restrict__ corr_arr)
{
    int i    = blockIdx.x * 4 + (threadIdx.x >> 6);
    int lane = threadIdx.x & 63;
    float4 v = part[(size_t)i * NCB + (lane & 31)];

    float M = v.x;
#pragma unroll
    for (int off = 32; off; off >>= 1) M = fmaxf(M, __shfl_xor(M, off));
    float L = (lane < 32) ? v.y * __expf(v.x - M) : 0.f;
#pragma unroll
    for (int off = 32; off; off >>= 1) L += __shfl_xor(L, off);
    float bm = v.x; int bi = __float_as_int(v.z);
#pragma unroll
    for (int off = 1; off < 32; off <<= 1) {   // first-index tiebreak
        float ov = __shfl_xor(bm, off);
        int   oi = __shfl_xor(bi, off);
        if (ov > bm || (ov == bm && oi < bi)) { bm = ov; bi = oi; }
    }
    float dg = __shfl(v.w, i >> 8);
    if (lane == 0) {
        loss_arr[i] = (M + logf(L)) - dg;
        corr_arr[i] = (bi == i) ? 1.0f : 0.0f;
    }
}

// ---------------------------------------------------------------------------
// Kernel 4: deterministic single-block mean reduction -> d_out[0..1]
// ---------------------------------------------------------------------------
__global__ __launch_bounds__(256) void finalize_kernel(
    const float* __restrict__ loss_arr, const float* __restrict__ corr_arr,
    float* __restrict__ out, int n)
{
    float a = 0.f, b = 0.f;
    for (int i = threadIdx.x; i < n; i += 256) { a += loss_arr[i]; b += corr_arr[i]; }
#pragma unroll
    for (int off = 32; off; off >>= 1) { a += __shfl_xor(a, off); b += __shfl_xor(b, off); }
    __shared__ float sa[4], sb[4];
    int wid = threadIdx.x >> 6, lane = threadIdx.x & 63;
    if (lane == 0) { sa[wid] = a; sb[wid] = b; }
    __syncthreads();
    if (threadIdx.x == 0) {
        out[0] = (sa[0] + sa[1] + sa[2] + sa[3]) / n;
        out[1] = (sb[0] + sb[1] + sb[2] + sb[3]) / n;
    }
}

extern "C" void kernel_launch(void* const* d_in, const int* in_sizes, int n_in,
                              void* d_out, int out_size, void* d_ws, size_t ws_size,
                              hipStream_t stream)
{
    const float* x = (const float*)d_in[0];
    const float* q = (const float*)d_in[1];
    const int n = in_sizes[0] / CDIM;   // 8192

    char* ws = (char*)d_ws;
    size_t sz_bf = (size_t)n * CDIM * sizeof(u16);   // 8 MB each
    u16* xh = (u16*)(ws);
    u16* qh = (u16*)(ws + sz_bf);
    char* p = ws + 2 * sz_bf;
    float4* part = (float4*)p; p += (size_t)n * NCB * sizeof(float4);  // 4 MB
    float* loss_arr = (float*)p; p += (size_t)n * 4;
    float* corr_arr = (float*)p;

    norm_split_kernel<<<(2 * n) / 4, 256, 0, stream>>>(x, q, xh, qh, n);

    sim_main_kernel<<<(n / BM) * (n / BN), 1024, 3 * BUFSZ, stream>>>(xh, qh, part);

    merge_kernel<<<n / 4, 256, 0, stream>>>(part, loss_arr, corr_arr);

    finalize_kernel<<<1, 256, 0, stream>>>(loss_arr, corr_arr, (float*)d_out, n);
}

// Round 8
// 122.262 us; speedup vs baseline: 2.6071x; 1.0028x over previous
//
#include <hip/hip_runtime.h>
#include <hip/hip_bf16.h>
#include <math.h>

#define CDIM 512
#define NROW 8192
#define BM 256
#define BN 256
#define BK 32
#define NT 16              // K tiles: 512/32
#define NCB 32             // column blocks (8192/256)
#define BUFSZ 32768        // A 16 KB + B 16 KB per K-tile buffer
#define TEMP_INV 10.0f

typedef unsigned short u16;
typedef u16  u16x8 __attribute__((ext_vector_type(8)));
typedef __bf16 bf16x8 __attribute__((ext_vector_type(8)));
typedef float  f32x4 __attribute__((ext_vector_type(4)));

static __device__ __forceinline__ float bf2f(u16 u) {
    return __uint_as_float(((unsigned)u) << 16);
}
static __device__ __forceinline__ u16 f2bf(float f) {
    unsigned u = __float_as_uint(f);
    return (u16)((u + 0x7FFFu + ((u >> 16) & 1u)) >> 16);  // RNE
}

static __device__ __forceinline__ void gload_lds16(const u16* g, char* l) {
    __builtin_amdgcn_global_load_lds(
        (const __attribute__((address_space(1))) void*)g,
        (__attribute__((address_space(3))) void*)l, 16, 0, 0);
}

// ---------------------------------------------------------------------------
// Kernel 1: row-normalize (fp32 math) -> bf16 (RNE). One wave per row.
// ---------------------------------------------------------------------------
__global__ __launch_bounds__(256) void norm_split_kernel(
    const float* __restrict__ x, const float* __restrict__ q,
    u16* __restrict__ xh, u16* __restrict__ qh, int n)
{
    int wave = blockIdx.x * 4 + (threadIdx.x >> 6);
    int lane = threadIdx.x & 63;
    const float* src; u16* dh; int row;
    if (wave < n) { src = x; dh = xh; row = wave; }
    else          { src = q; dh = qh; row = wave - n; }

    const float4* p = reinterpret_cast<const float4*>(src + (size_t)row * CDIM);
    float4 a = p[lane * 2];
    float4 b = p[lane * 2 + 1];
    float v[8] = {a.x, a.y, a.z, a.w, b.x, b.y, b.z, b.w};
    float ss = 0.f;
#pragma unroll
    for (int j = 0; j < 8; ++j) ss += v[j] * v[j];
#pragma unroll
    for (int off = 32; off; off >>= 1) ss += __shfl_xor(ss, off);
    float scale = 1.0f / fmaxf(sqrtf(ss), 1e-12f);

    u16 h[8] __attribute__((aligned(16)));
#pragma unroll
    for (int j = 0; j < 8; ++j) h[j] = f2bf(v[j] * scale);
    *(u16x8*)&dh[(size_t)row * CDIM + lane * 8] = *(u16x8*)h;
}

// ---------------------------------------------------------------------------
// Kernel 2: 256x256-tile bf16 GEMM (K=512), triple-buffered BK=32, one
// barrier per K-tile. 1024 threads = 16 waves (4 wm x 4 wn), wave tile 64x64
// (identical per-wave pattern to R5: conflict-verified chunk swizzle
// physical_chunk = logical_chunk ^ ((row>>1)&3), applied on both sides).
// XCD blocking: xcd = orig&7 owns all 32 rb x 4 cb, rb-outer order ->
// co-resident L2 footprint/XCD = 8 A-panels (2MB) + 4 B-panels (1MB) = 3MB.
// Fused epilogue: per-row (max, sum-exp, argmax) partials + in-tile diag
// (diag tile iff rb==cb), packed float4 -> part[row][cb].
// ---------------------------------------------------------------------------
__global__ __launch_bounds__(1024, 4) void sim_main_kernel(
    const u16* __restrict__ xh, const u16* __restrict__ qh,
    float4* __restrict__ part)
{
    extern __shared__ __align__(16) char smem[];   // 3 * 32768 = 96 KB
    const int t = threadIdx.x, lane = t & 63, wid = t >> 6;
    const int wm = wid >> 2, wn = wid & 3;

    // XCD-resident blocking: orig&7 = XCD (hw round-robin), rb outer, cb inner
    const int orig = blockIdx.x;
    const int xcd = orig & 7, s = orig >> 3;       // s in [0,128)
    const int rb = s >> 2;                          // 0..31
    const int cb = xcd * 4 + (s & 3);               // 0..31
    const int row0 = rb * BM, col0 = cb * BN;

    // staging sources (per-lane): thread t fills LDS row (t>>2), physical
    // chunk (t&3); global chunk = (t&3) ^ ((row>>1)&3) = (t&3) ^ ((t>>3)&3)
    const int schunk = (t & 3) ^ ((t >> 3) & 3);
    const u16* sa = xh + (size_t)(row0 + (t >> 2)) * CDIM + schunk * 8;
    const u16* sb = qh + (size_t)(col0 + (t >> 2)) * CDIM + schunk * 8;
    const unsigned dstw = (unsigned)wid * 1024u;   // wave-uniform dest

    auto stage = [&](int kt) {
        char* b = smem + (kt % 3) * BUFSZ;
        const int ko = kt * BK;
        gload_lds16(sa + ko, b + dstw);             // A: rows 0..255 x 32k
        gload_lds16(sb + ko, b + 16384 + dstw);     // B: rows 0..255 x 32k
    };

    // frag read offsets (row stride 64 B); physical chunk = slot ^ ((row>>1)&3)
    const unsigned kxc = ((unsigned)((lane >> 4) ^ ((lane >> 1) & 3))) * 16u;
    const unsigned aro = ((unsigned)(wm * 64 + (lane & 15))) * 64u + kxc;
    const unsigned bro = 16384u + ((unsigned)(wn * 64 + (lane & 15))) * 64u + kxc;

    f32x4 acc[4][4];
#pragma unroll
    for (int i = 0; i < 4; ++i)
#pragma unroll
        for (int j = 0; j < 4; ++j) acc[i][j] = (f32x4){0.f, 0.f, 0.f, 0.f};

    // prologue: lead-2
    stage(0); stage(1);
    asm volatile("s_waitcnt vmcnt(2)" ::: "memory");   // stage(0) landed
    __builtin_amdgcn_s_barrier();
    asm volatile("" ::: "memory");

    for (int kt = 0; kt < NT; ++kt) {
        const char* buf = smem + (kt % 3) * BUFSZ;
        // issue next-next stage FIRST (loads fly during reads+MFMA)
        if (kt < NT - 2) stage(kt + 2);
        bf16x8 afr[4], bfr[4];
#pragma unroll
        for (int mf = 0; mf < 4; ++mf) afr[mf] = *(const bf16x8*)(buf + aro + mf * 1024u);
#pragma unroll
        for (int nf = 0; nf < 4; ++nf) bfr[nf] = *(const bf16x8*)(buf + bro + nf * 1024u);

        __builtin_amdgcn_s_setprio(1);
#pragma unroll
        for (int mf = 0; mf < 4; ++mf)
#pragma unroll
            for (int nf = 0; nf < 4; ++nf)
                acc[mf][nf] = __builtin_amdgcn_mfma_f32_16x16x32_bf16(
                    afr[mf], bfr[nf], acc[mf][nf], 0, 0, 0);
        __builtin_amdgcn_s_setprio(0);

        if (kt < NT - 2)       { asm volatile("s_waitcnt vmcnt(2)" ::: "memory"); }
        else if (kt == NT - 2) { asm volatile("s_waitcnt vmcnt(0)" ::: "memory"); }
        // reads of buf[kt%3] must complete before kt+1 stages into it (kt+3%3)
        asm volatile("s_waitcnt lgkmcnt(0)" ::: "memory");
        __builtin_amdgcn_s_barrier();
        asm volatile("" ::: "memory");
    }

    // ---- epilogue: per-row (max, sum-exp, argmax) + in-tile diag ----
    // C/D layout: row = (lane>>4)*4 + reg, col = lane&15 (verified R1-R5).
    __syncthreads();
    float* sm = (float*)smem;              // [256][4] row max (logit units)
    float* sl = sm + 1024;                 // [256][4] sum exp
    int*   si = (int*)(sl + 1024);         // [256][4] argmax col
    float* sd = (float*)(si + 1024);       // [256] diag (logit units)
    const int g = lane >> 4;
#pragma unroll
    for (int mf = 0; mf < 4; ++mf) {
#pragma unroll
        for (int r = 0; r < 4; ++r) {
            const int row_loc  = wm * 64 + mf * 16 + g * 4 + r;
            const int row_glob = row0 + row_loc;
            const int ci = col0 + wn * 64 + (lane & 15);
            float vmax = acc[mf][0][r];
            int cbest = ci;
#pragma unroll
            for (int nf = 1; nf < 4; ++nf) {
                float v = acc[mf][nf][r];
                if (v > vmax) { vmax = v; cbest = ci + nf * 16; }
                if (ci + nf * 16 == row_glob) sd[row_loc] = v * TEMP_INV;
            }
            if (ci == row_glob) sd[row_loc] = acc[mf][0][r] * TEMP_INV;
#pragma unroll
            for (int m = 1; m < 16; m <<= 1) {
                float ov = __shfl_xor(vmax, m);
                int   oi = __shfl_xor(cbest, m);
                if (ov > vmax || (ov == vmax && oi < cbest)) { vmax = ov; cbest = oi; }
            }
            float ssum = 0.f;
#pragma unroll
            for (int nf = 0; nf < 4; ++nf)
                ssum += __expf((acc[mf][nf][r] - vmax) * TEMP_INV);
#pragma unroll
            for (int m = 1; m < 16; m <<= 1) ssum += __shfl_xor(ssum, m);
            if ((lane & 15) == 0) {
                sm[row_loc * 4 + wn] = vmax * TEMP_INV;
                sl[row_loc * 4 + wn] = ssum;
                si[row_loc * 4 + wn] = cbest;
            }
        }
    }
    __syncthreads();
    if (t < 256) {
        float M = sm[t * 4];
#pragma unroll
        for (int w = 1; w < 4; ++w) M = fmaxf(M, sm[t * 4 + w]);
        float L = 0.f;
#pragma unroll
        for (int w = 0; w < 4; ++w) L += sl[t * 4 + w] * __expf(sm[t * 4 + w] - M);
        float bv = -1e30f; int bi = 0;
#pragma unroll
        for (int w = 0; w < 4; ++w) {      // ascending wn: first-index tiebreak
            float v = sm[t * 4 + w];
            if (v > bv) { bv = v; bi = si[t * 4 + w]; }
        }
        part[(size_t)(row0 + t) * NCB + cb] =
            make_float4(M, L, __int_as_float(bi), sd[t]);
    }
}

// ---------------------------------------------------------------------------
// Kernel 3: per-row merge of 32 chunk partials -> loss_i / correct_i.
// One wave per row; lanes>=32 hold duplicates (zeroed for the sum).
// Diag comes from chunk (i>>8).
// ---------------------------------------------------------------------------
__global__ __launch_bounds__(256) void merge_kernel(
    const float4* __restrict__ part,
    float* __restrict__ loss_arr, float* __restrict__ corr_arr)
{
    int i    = blockIdx.x * 4 + (threadIdx.x >> 6);
    int lane = threadIdx.x & 63;
    float4 v = part[(size_t)i * NCB + (lane & 31)];

    float M = v.x;
#pragma unroll
    for (int off = 32; off; off >>= 1) M = fmaxf(M, __shfl_xor(M, off));
    float L = (lane < 32) ? v.y * __expf(v.x - M) : 0.f;
#pragma unroll
    for (int off = 32; off; off >>= 1) L += __shfl_xor(L, off);
    float bm = v.x; int bi = __float_as_int(v.z);
#pragma unroll
    for (int off = 1; off < 32; off <<= 1) {   // first-index tiebreak
        float ov = __shfl_xor(bm, off);
        int   oi = __shfl_xor(bi, off);
        if (ov > bm || (ov == bm && oi < bi)) { bm = ov; bi = oi; }
    }
    float dg = __shfl(v.w, i >> 8);
    if (lane == 0) {
        loss_arr[i] = (M + logf(L)) - dg;
        corr_arr[i] = (bi == i) ? 1.0f : 0.0f;
    }
}

// ---------------------------------------------------------------------------
// Kernel 4: deterministic single-block mean reduction -> d_out[0..1]
// ---------------------------------------------------------------------------
__global__ __launch_bounds__(256) void finalize_kernel(
    const float* __restrict__ loss_arr, const float* __restrict__ corr_arr,
    float* __restrict__ out, int n)
{
    float a = 0.f, b = 0.f;
    for (int i = threadIdx.x; i < n; i += 256) { a += loss_arr[i]; b += corr_arr[i]; }
#pragma unroll
    for (int off = 32; off; off >>= 1) { a += __shfl_xor(a, off); b += __shfl_xor(b, off); }
    __shared__ float sa[4], sb[4];
    int wid = threadIdx.x >> 6, lane = threadIdx.x & 63;
    if (lane == 0) { sa[wid] = a; sb[wid] = b; }
    __syncthreads();
    if (threadIdx.x == 0) {
        out[0] = (sa[0] + sa[1] + sa[2] + sa[3]) / n;
        out[1] = (sb[0] + sb[1] + sb[2] + sb[3]) / n;
    }
}

extern "C" void kernel_launch(void* const* d_in, const int* in_sizes, int n_in,
                              void* d_out, int out_size, void* d_ws, size_t ws_size,
                              hipStream_t stream)
{
    const float* x = (const float*)d_in[0];
    const float* q = (const float*)d_in[1];
    const int n = in_sizes[0] / CDIM;   // 8192

    char* ws = (char*)d_ws;
    size_t sz_bf = (size_t)n * CDIM * sizeof(u16);   // 8 MB each
    u16* xh = (u16*)(ws);
    u16* qh = (u16*)(ws + sz_bf);
    char* p = ws + 2 * sz_bf;
    float4* part = (float4*)p; p += (size_t)n * NCB * sizeof(float4);  // 4 MB
    float* loss_arr = (float*)p; p += (size_t)n * 4;
    float* corr_arr = (float*)p;

    norm_split_kernel<<<(2 * n) / 4, 256, 0, stream>>>(x, q, xh, qh, n);

    sim_main_kernel<<<(n / BM) * (n / BN), 1024, 3 * BUFSZ, stream>>>(xh, qh, part);

    merge_kernel<<<n / 4, 256, 0, stream>>>(part, loss_arr, corr_arr);

    finalize_kernel<<<1, 256, 0, stream>>>(loss_arr, corr_arr, (float*)d_out, n);
}